// Round 2
// baseline (11955.093 us; speedup 1.0000x reference)
//
#include <hip/hip_runtime.h>

#define B_   8
#define C_   256
#define R_   14
#define R2   196
#define N3   2744      // 14^3
#define NH   4
#define KD   16
#define DV   64
#define QKVO 96        // 2*KD + DV
#define MT   64        // m-tile in attention
#define NTILE 43       // ceil(N3/MT)

__device__ __forceinline__ int iabs(int v){ return v < 0 ? -v : v; }

// ---------------------------------------------------------------------------
// QKV: y[o,n] = sum_c W[o,c] * feat[c,n]; feat = x_chunk (+ prev attn out)
// grid (11, B, 4), block 256; blockIdx.z picks 24 of the 96 outputs
// ---------------------------------------------------------------------------
__global__ __launch_bounds__(256)
void qkv_kernel(const float* __restrict__ x, const float* __restrict__ h,
                const float* __restrict__ W, const float* __restrict__ sc,
                const float* __restrict__ bi,
                float* __restrict__ q0, float* __restrict__ kb, float* __restrict__ vb,
                int head)
{
    int b = blockIdx.y;
    int og = blockIdx.z;                  // o in [og*24, og*24+24)
    int n = blockIdx.x * 256 + threadIdx.x;
    if (n >= N3) return;

    float f[64];
    const float* xb = x + ((size_t)b * C_ + head * DV) * N3 + n;
    if (head == 0) {
#pragma unroll
        for (int c = 0; c < 64; c++) f[c] = xb[(size_t)c * N3];
    } else {
        const float* hb = h + ((size_t)b * C_ + (head - 1) * DV) * N3 + n;
#pragma unroll
        for (int c = 0; c < 64; c++) f[c] = xb[(size_t)c * N3] + hb[(size_t)c * N3];
    }

    const float* Wh  = W  + head * QKVO * 64;   // uniform across threads -> s_loads
    const float* sch = sc + head * QKVO;
    const float* bih = bi + head * QKVO;

    float* qo = q0 + (size_t)b * KD * N3 + n;
    float* ko = kb + (size_t)b * KD * N3 + n;
    float* vo = vb + (size_t)b * DV * N3 + n;

    for (int oo = 0; oo < 24; oo++) {
        int o = og * 24 + oo;
        float acc = 0.f;
#pragma unroll
        for (int c = 0; c < 64; c++) acc += Wh[o * 64 + c] * f[c];
        acc = acc * sch[o] + bih[o];
        if (o < KD)            qo[(size_t)o * N3] = acc;
        else if (o < 2 * KD)   ko[(size_t)(o - KD) * N3] = acc;
        else                   vo[(size_t)(o - 2 * KD) * N3] = acc;
    }
}

// ---------------------------------------------------------------------------
// Depthwise 5x5x5 SAME conv on q, in-place (reads LDS copy), + scale/bias
// grid (KD, B), block 256
// ---------------------------------------------------------------------------
__global__ __launch_bounds__(256)
void dwconv_kernel(float* __restrict__ q0, const float* __restrict__ Wdw,
                   const float* __restrict__ dsc, const float* __restrict__ dbi,
                   int head)
{
    __shared__ float ch[N3];
    int b = blockIdx.y, c = blockIdx.x;
    int t = threadIdx.x;
    float* qc = q0 + ((size_t)b * KD + c) * N3;
    for (int i = t; i < N3; i += 256) ch[i] = qc[i];
    __syncthreads();

    const float* w = Wdw + (head * KD + c) * 125;   // uniform -> s_loads
    float scl = dsc[head * KD + c], bia = dbi[head * KD + c];

    for (int i = t; i < N3; i += 256) {
        int xx = i / R2; int rem = i - xx * R2; int yy = rem / R_; int zz = rem - yy * R_;
        float acc = 0.f;
#pragma unroll
        for (int a = 0; a < 5; a++) {
            int xa = xx + a - 2;
            if ((unsigned)xa >= (unsigned)R_) continue;
#pragma unroll
            for (int bb = 0; bb < 5; bb++) {
                int yb = yy + bb - 2;
                if ((unsigned)yb >= (unsigned)R_) continue;
#pragma unroll
                for (int cc = 0; cc < 5; cc++) {
                    int zc = zz + cc - 2;
                    if ((unsigned)zc >= (unsigned)R_) continue;
                    acc += w[a * 25 + bb * 5 + cc] * ch[xa * R2 + yb * R_ + zc];
                }
            }
        }
        qc[i] = acc * scl + bia;
    }
}

// ---------------------------------------------------------------------------
// Fused attention: 32 q-rows/block; thread = (row-pair p of 16, m-slice s of 16).
// Per-tile deferred max (thr=8), reg-staged prefetch, no per-m branches.
// grid (86, B), block 256
// ---------------------------------------------------------------------------
__global__ __launch_bounds__(256, 2)
void attn_kernel(const float* __restrict__ qb, const float* __restrict__ kg0,
                 const float* __restrict__ vg0, float* __restrict__ h,
                 const float* __restrict__ abias, int head)
{
    __shared__ float kt[MT][20];     // [m][d], stride 20: conflict-free f4 reads
    __shared__ float vt[MT][68];     // [m][c], stride 68: conflict-free f4 reads
    __shared__ int   mxa[MT];
    __shared__ int   mya[MT];
    __shared__ float ab[R2];

    int b = blockIdx.y;
    int qbase = blockIdx.x * 32;
    int t = threadIdx.x;
    int s = t & 15;          // m-slice
    int p = t >> 4;          // row-pair index [0,16)
    int rA = qbase + p, rB = rA + 16;
    bool vA = rA < N3, vB = rB < N3;

    if (t < R2) ab[t] = abias[head * R2 + t];

    const float* qq = qb + (size_t)b * KD * N3;
    float qA[KD], qB[KD];
#pragma unroll
    for (int d = 0; d < KD; d++) {
        qA[d] = vA ? qq[(size_t)d * N3 + rA] : 0.f;
        qB[d] = vB ? qq[(size_t)d * N3 + rB] : 0.f;
    }
    int nxA = vA ? rA / R2 : 0; int nyA = vA ? (rA - nxA * R2) / R_ : 0;
    int nxB = vB ? rB / R2 : 0; int nyB = vB ? (rB - nxB * R2) / R_ : 0;

    float mA = -3.0e38f, lA = 0.f, mB = -3.0e38f, lB = 0.f;
    float4 aA[16], aB[16];
#pragma unroll
    for (int r = 0; r < 16; r++) { aA[r] = make_float4(0,0,0,0); aB[r] = make_float4(0,0,0,0); }

    const float* kg = kg0 + (size_t)b * KD * N3;
    const float* vg = vg0 + (size_t)b * DV * N3;

    // staging coords: this thread stages rows mmS for d/c = dS+4k
    int mmS = t & 63, dS = t >> 6;
    float kreg[4], vreg[16];
    {   // prefetch tile 0 (m = mmS < 64 < N3, no guard)
#pragma unroll
        for (int k = 0; k < 4; k++)  kreg[k] = kg[(size_t)(dS + 4*k) * N3 + mmS];
#pragma unroll
        for (int k = 0; k < 16; k++) vreg[k] = vg[(size_t)(dS + 4*k) * N3 + mmS];
    }

    for (int t0 = 0; t0 < NTILE; t0++) {
        int m0 = t0 * MT;
        __syncthreads();                       // prev tile's LDS reads done
#pragma unroll
        for (int k = 0; k < 4; k++)  kt[mmS][dS + 4*k] = kreg[k];
#pragma unroll
        for (int k = 0; k < 16; k++) vt[mmS][dS + 4*k] = vreg[k];
        if (t < MT) {
            int m = m0 + t;
            int mc = m < N3 ? m : 0;
            int mx = mc / R2; int rem = mc - mx * R2;
            mxa[t] = mx; mya[t] = rem / R_;
        }
        {   // prefetch next tile (latency hides under compute below)
            int m1 = m0 + MT + mmS;
            bool ok = m1 < N3;
#pragma unroll
            for (int k = 0; k < 4; k++)  kreg[k] = ok ? kg[(size_t)(dS + 4*k) * N3 + m1] : 0.f;
#pragma unroll
            for (int k = 0; k < 16; k++) vreg[k] = ok ? vg[(size_t)(dS + 4*k) * N3 + m1] : 0.f;
        }
        __syncthreads();                       // this tile's LDS ready

        // phase 1: logits for this thread's 4 m's
        float lgA[4], lgB[4];
#pragma unroll
        for (int j = 0; j < 4; j++) {
            int mm = s + j * 16;
            float kk[16];
            *(float4*)&kk[0]  = *(const float4*)&kt[mm][0];
            *(float4*)&kk[4]  = *(const float4*)&kt[mm][4];
            *(float4*)&kk[8]  = *(const float4*)&kt[mm][8];
            *(float4*)&kk[12] = *(const float4*)&kt[mm][12];
            float dA = 0.f, dB = 0.f;
#pragma unroll
            for (int d = 0; d < 16; d++) { dA += qA[d] * kk[d]; dB += qB[d] * kk[d]; }
            int mx = mxa[mm], my = mya[mm];
            lgA[j] = 0.25f * dA + ab[iabs(nxA - mx) * R_ + iabs(nyA - my)];
            lgB[j] = 0.25f * dB + ab[iabs(nxB - mx) * R_ + iabs(nyB - my)];
            if (m0 + mm >= N3) { lgA[j] = -3.0e38f; lgB[j] = -3.0e38f; }
        }

        // phase 2: deferred-max rescale (at most once per tile, thr=8)
        float tAm = fmaxf(fmaxf(lgA[0], lgA[1]), fmaxf(lgA[2], lgA[3]));
        float tBm = fmaxf(fmaxf(lgB[0], lgB[1]), fmaxf(lgB[2], lgB[3]));
        if (tAm > mA + 8.0f) {
            float fr = __expf(mA - tAm); lA *= fr; mA = tAm;
#pragma unroll
            for (int r = 0; r < 16; r++) { aA[r].x *= fr; aA[r].y *= fr; aA[r].z *= fr; aA[r].w *= fr; }
        }
        if (tBm > mB + 8.0f) {
            float fr = __expf(mB - tBm); lB *= fr; mB = tBm;
#pragma unroll
            for (int r = 0; r < 16; r++) { aB[r].x *= fr; aB[r].y *= fr; aB[r].z *= fr; aB[r].w *= fr; }
        }
        float wA[4], wB[4];
#pragma unroll
        for (int j = 0; j < 4; j++) {
            wA[j] = __expf(lgA[j] - mA); lA += wA[j];
            wB[j] = __expf(lgB[j] - mB); lB += wB[j];
        }

        // phase 3: accumulate V
#pragma unroll
        for (int j = 0; j < 4; j++) {
            int mm = s + j * 16;
#pragma unroll
            for (int r = 0; r < 16; r++) {
                float4 vv = *(const float4*)&vt[mm][r * 4];
                aA[r].x += wA[j] * vv.x; aA[r].y += wA[j] * vv.y;
                aA[r].z += wA[j] * vv.z; aA[r].w += wA[j] * vv.w;
                aB[r].x += wB[j] * vv.x; aB[r].y += wB[j] * vv.y;
                aB[r].z += wB[j] * vv.z; aB[r].w += wB[j] * vv.w;
            }
        }
    }

    // combine 16 m-slices (lanes differing in bits 0..3) via butterfly
#pragma unroll
    for (int mask = 1; mask < 16; mask <<= 1) {
        float moA = __shfl_xor(mA, mask); float loA = __shfl_xor(lA, mask);
        float nmA = fmaxf(mA, moA);
        float fsA = __expf(mA - nmA), foA = __expf(moA - nmA);
        lA = lA * fsA + loA * foA;
        float moB = __shfl_xor(mB, mask); float loB = __shfl_xor(lB, mask);
        float nmB = fmaxf(mB, moB);
        float fsB = __expf(mB - nmB), foB = __expf(moB - nmB);
        lB = lB * fsB + loB * foB;
#pragma unroll
        for (int r = 0; r < 16; r++) {
            float vx;
            vx = __shfl_xor(aA[r].x, mask); aA[r].x = aA[r].x * fsA + vx * foA;
            vx = __shfl_xor(aA[r].y, mask); aA[r].y = aA[r].y * fsA + vx * foA;
            vx = __shfl_xor(aA[r].z, mask); aA[r].z = aA[r].z * fsA + vx * foA;
            vx = __shfl_xor(aA[r].w, mask); aA[r].w = aA[r].w * fsA + vx * foA;
            vx = __shfl_xor(aB[r].x, mask); aB[r].x = aB[r].x * fsB + vx * foB;
            vx = __shfl_xor(aB[r].y, mask); aB[r].y = aB[r].y * fsB + vx * foB;
            vx = __shfl_xor(aB[r].z, mask); aB[r].z = aB[r].z * fsB + vx * foB;
            vx = __shfl_xor(aB[r].w, mask); aB[r].w = aB[r].w * fsB + vx * foB;
        }
        mA = nmA; mB = nmB;
    }

    float iA = 1.f / lA, iB = 1.f / lB;
    float* hb = h + ((size_t)b * C_ + head * DV) * N3;
    // slice s writes channels 4s..4s+3 for both of its rows
    {
        float oa[4] = { aA[s].x, aA[s].y, aA[s].z, aA[s].w };
        float ob[4] = { aB[s].x, aB[s].y, aB[s].z, aB[s].w };
#pragma unroll
        for (int e = 0; e < 4; e++) {
            if (vA) hb[(size_t)(4 * s + e) * N3 + rA] = oa[e] * iA;
            if (vB) hb[(size_t)(4 * s + e) * N3 + rB] = ob[e] * iB;
        }
    }
}

// ---------------------------------------------------------------------------
// Projection: out[o,n] = psc[o]*sum_c Wp[o,c]*relu(h[c,n]) + pbi[o]
// grid (98, B), block 128; thread handles o=t and o=t+128 over 28 n's
// ---------------------------------------------------------------------------
__global__ __launch_bounds__(128)
void proj_kernel(const float* __restrict__ h, const float* __restrict__ Wp,
                 const float* __restrict__ psc, const float* __restrict__ pbi,
                 float* __restrict__ out)
{
    __shared__ float ht[256][28];
    int b = blockIdx.y; int n0 = blockIdx.x * 28; int t = threadIdx.x;

    const float* hb = h + (size_t)b * C_ * N3 + n0;
    for (int i = t; i < 256 * 28; i += 128) {
        int c = i / 28; int j = i - c * 28;
        float v = hb[(size_t)c * N3 + j];
        ht[c][j] = v > 0.f ? v : 0.f;
    }
    __syncthreads();

    int o0 = t, o1 = t + 128;
    float a0[28], a1[28];
#pragma unroll
    for (int j = 0; j < 28; j++) { a0[j] = 0.f; a1[j] = 0.f; }

    const float4* w04 = (const float4*)(Wp + (size_t)o0 * 256);
    const float4* w14 = (const float4*)(Wp + (size_t)o1 * 256);
    for (int c4 = 0; c4 < 64; c4++) {
        float4 wa = w04[c4], wb = w14[c4];
        int cb = c4 * 4;
#pragma unroll
        for (int u = 0; u < 4; u++) {
            float W0 = (u == 0) ? wa.x : (u == 1) ? wa.y : (u == 2) ? wa.z : wa.w;
            float W1 = (u == 0) ? wb.x : (u == 1) ? wb.y : (u == 2) ? wb.z : wb.w;
#pragma unroll
            for (int j = 0; j < 28; j++) {
                a0[j] += W0 * ht[cb + u][j];
                a1[j] += W1 * ht[cb + u][j];
            }
        }
    }

    float s0 = psc[o0], b0 = pbi[o0], s1 = psc[o1], b1 = pbi[o1];
    float* ob0 = out + ((size_t)b * C_ + o0) * N3 + n0;
    float* ob1 = out + ((size_t)b * C_ + o1) * N3 + n0;
#pragma unroll
    for (int j = 0; j < 28; j++) {
        ob0[j] = a0[j] * s0 + b0;
        ob1[j] = a1[j] * s1 + b1;
    }
}

// ---------------------------------------------------------------------------
extern "C" void kernel_launch(void* const* d_in, const int* in_sizes, int n_in,
                              void* d_out, int out_size, void* d_ws, size_t ws_size,
                              hipStream_t stream)
{
    const float* x    = (const float*)d_in[0];
    const float* Wqkv = (const float*)d_in[1];
    const float* qsc  = (const float*)d_in[2];
    const float* qbi  = (const float*)d_in[3];
    const float* Wdw  = (const float*)d_in[4];
    const float* dsc  = (const float*)d_in[5];
    const float* dbi  = (const float*)d_in[6];
    const float* Wp   = (const float*)d_in[7];
    const float* psc  = (const float*)d_in[8];
    const float* pbi  = (const float*)d_in[9];
    const float* ab   = (const float*)d_in[10];
    // d_in[11] = bias_idx: unused (computed analytically)

    float* out = (float*)d_out;
    float* ws  = (float*)d_ws;
    float* q0 = ws;                                   // B*KD*N3
    float* kb = q0 + (size_t)B_ * KD * N3;            // B*KD*N3
    float* vb = kb + (size_t)B_ * KD * N3;            // B*DV*N3
    float* h  = vb + (size_t)B_ * DV * N3;            // B*C_*N3 (pre-relu)

    for (int head = 0; head < NH; head++) {
        qkv_kernel<<<dim3(11, B_, 4), 256, 0, stream>>>(x, h, Wqkv, qsc, qbi, q0, kb, vb, head);
        dwconv_kernel<<<dim3(KD, B_), 256, 0, stream>>>(q0, Wdw, dsc, dbi, head);
        attn_kernel<<<dim3(86, B_), 256, 0, stream>>>(q0, kb, vb, h, ab, head);
    }
    proj_kernel<<<dim3(98, B_), 128, 0, stream>>>(h, Wp, psc, pbi, out);
}

// Round 3
// 5162.605 us; speedup vs baseline: 2.3157x; 2.3157x over previous
//
#include <hip/hip_runtime.h>

#define B_   8
#define C_   256
#define R_   14
#define R2   196
#define N3   2744      // 14^3
#define NP   2752      // padded (43*64) so attention tiles never read OOB
#define NH   4
#define KD   16
#define DV   64
#define QKVO 96        // 2*KD + DV
#define MT   64        // m-tile in attention
#define NTILE 43

__device__ __forceinline__ int iabs(int v){ return v < 0 ? -v : v; }

// ---------------------------------------------------------------------------
// QKV: y[o,n] = sum_c W[o,c] * feat[c,n]; feat = x_chunk (+ prev attn out)
// grid (11, B, 4), block 256
// ---------------------------------------------------------------------------
__global__ __launch_bounds__(256)
void qkv_kernel(const float* __restrict__ x, const float* __restrict__ h,
                const float* __restrict__ W, const float* __restrict__ sc,
                const float* __restrict__ bi,
                float* __restrict__ q0, float* __restrict__ kb, float* __restrict__ vb,
                int head)
{
    int b = blockIdx.y;
    int og = blockIdx.z;
    int n = blockIdx.x * 256 + threadIdx.x;
    if (n >= N3) return;

    float f[64];
    const float* xb = x + ((size_t)b * C_ + head * DV) * N3 + n;
    if (head == 0) {
#pragma unroll
        for (int c = 0; c < 64; c++) f[c] = xb[(size_t)c * N3];
    } else {
        const float* hb = h + ((size_t)b * C_ + (head - 1) * DV) * N3 + n;
#pragma unroll
        for (int c = 0; c < 64; c++) f[c] = xb[(size_t)c * N3] + hb[(size_t)c * N3];
    }

    const float* Wh  = W  + head * QKVO * 64;   // uniform -> s_loads
    const float* sch = sc + head * QKVO;
    const float* bih = bi + head * QKVO;

    float* qo = q0 + (size_t)b * KD * NP + n;
    float* ko = kb + (size_t)b * KD * NP + n;
    float* vo = vb + (size_t)b * DV * NP + n;

    for (int oo = 0; oo < 24; oo++) {
        int o = og * 24 + oo;
        float acc = 0.f;
#pragma unroll
        for (int c = 0; c < 64; c++) acc += Wh[o * 64 + c] * f[c];
        acc = acc * sch[o] + bih[o];
        if (o < KD)            qo[(size_t)o * NP] = acc;
        else if (o < 2 * KD)   ko[(size_t)(o - KD) * NP] = acc;
        else                   vo[(size_t)(o - 2 * KD) * NP] = acc;
    }
}

// ---------------------------------------------------------------------------
// Depthwise 5x5x5 SAME conv on q (padded stride NP), + scale/bias
// grid (KD, B), block 256
// ---------------------------------------------------------------------------
__global__ __launch_bounds__(256)
void dwconv_kernel(float* __restrict__ q0, const float* __restrict__ Wdw,
                   const float* __restrict__ dsc, const float* __restrict__ dbi,
                   int head)
{
    __shared__ float ch[N3];
    int b = blockIdx.y, c = blockIdx.x;
    int t = threadIdx.x;
    float* qc = q0 + ((size_t)b * KD + c) * NP;
    for (int i = t; i < N3; i += 256) ch[i] = qc[i];
    __syncthreads();

    const float* w = Wdw + (head * KD + c) * 125;
    float scl = dsc[head * KD + c], bia = dbi[head * KD + c];

    for (int i = t; i < N3; i += 256) {
        int xx = i / R2; int rem = i - xx * R2; int yy = rem / R_; int zz = rem - yy * R_;
        float acc = 0.f;
#pragma unroll
        for (int a = 0; a < 5; a++) {
            int xa = xx + a - 2;
            if ((unsigned)xa >= (unsigned)R_) continue;
#pragma unroll
            for (int bb = 0; bb < 5; bb++) {
                int yb = yy + bb - 2;
                if ((unsigned)yb >= (unsigned)R_) continue;
#pragma unroll
                for (int cc = 0; cc < 5; cc++) {
                    int zc = zz + cc - 2;
                    if ((unsigned)zc >= (unsigned)R_) continue;
                    acc += w[a * 25 + bb * 5 + cc] * ch[xa * R2 + yb * R_ + zc];
                }
            }
        }
        qc[i] = acc * scl + bia;
    }
}

// ---------------------------------------------------------------------------
// Fused attention v3: 32 q-rows/block, A/B phase split.
// A: (aP 0..15 -> rows aP, aP+16; aS 0..15 -> m-chunk 4*aS): logits+softmax w -> LDS
// B: (bP wave -> rows 8bP..+7; bC -> ch 8bC..+7; bS -> m pairs): PV, acc 8x8
// grid (86, B), block 256
// ---------------------------------------------------------------------------
__global__ __launch_bounds__(256, 4)
void attn_kernel(const float* __restrict__ q0, const float* __restrict__ kb,
                 const float* __restrict__ vb, float* __restrict__ h,
                 const float* __restrict__ abias, int head)
{
    __shared__ float kt[16][68];    // K tile, [d][m], stride 68
    __shared__ float vt[64][68];    // V tile, [c][m], stride 68 (reused as out-transpose buf)
    __shared__ float wt[64][36];    // softmax weights [m][row]
    __shared__ float ab[224];
    __shared__ float fra[32];
    __shared__ float linv[32];

    const int b = blockIdx.y;
    const int qbase = blockIdx.x * 32;
    const int t = threadIdx.x;

    const int aP = t >> 4;          // 0..15
    const int aS = t & 15;          // m-chunk 4*aS
    const int bP = t >> 6;          // wave id: rows 8bP..8bP+7
    const int bC = (t >> 3) & 7;    // ch 8bC..8bC+7
    const int bS = t & 7;           // m pairs 2bS+16j

    if (t < 196) ab[t] = abias[head * R2 + t];
    else if (t < 224) ab[t] = 0.f;

    const int rA0 = qbase + aP;
    const int rA1 = qbase + aP + 16;
    const bool v1 = rA1 < N3;       // rA0 always < N3

    const float* qq = q0 + (size_t)b * KD * NP;
    float qa[16], qb_[16];
#pragma unroll
    for (int d = 0; d < 16; d++) {
        qa[d]  = qq[(size_t)d * NP + rA0];
        qb_[d] = v1 ? qq[(size_t)d * NP + rA1] : 0.f;
    }
    int nx0 = rA0 / R2, ny0 = (rA0 - nx0 * R2) / R_;
    int rc1 = v1 ? rA1 : 0;
    int nx1 = rc1 / R2, ny1 = (rc1 - nx1 * R2) / R_;

    float mr0 = -3.0e38f, mr1 = -3.0e38f, lp0 = 0.f, lp1 = 0.f;
    float acc[8][8];
#pragma unroll
    for (int r = 0; r < 8; r++)
#pragma unroll
        for (int e = 0; e < 8; e++) acc[r][e] = 0.f;

    const float* kg = kb + (size_t)b * KD * NP;
    const float* vg = vb + (size_t)b * DV * NP;

    // staging ids
    const int kc = t >> 4, kq = t & 15;     // K: row kc (0..15), 4 floats at 4*kq
    const int vc = t >> 2, vq = t & 3;      // V: row vc (0..63), 16 floats at 16*vq

    for (int t0 = 0; t0 < NTILE; t0++) {
        const int m0 = t0 * MT;
        __syncthreads();                                    // prev tile fully consumed
        {   // stage K (buffers padded: no OOB)
            float4 k4 = *(const float4*)(kg + (size_t)kc * NP + m0 + 4 * kq);
            *(float4*)&kt[kc][4 * kq] = k4;
        }
        {   // stage V
            const float* vsrc = vg + (size_t)vc * NP + m0 + 16 * vq;
            float4 a0 = ((const float4*)vsrc)[0];
            float4 a1 = ((const float4*)vsrc)[1];
            float4 a2 = ((const float4*)vsrc)[2];
            float4 a3 = ((const float4*)vsrc)[3];
            float* vdst = &vt[vc][16 * vq];
            ((float4*)vdst)[0] = a0; ((float4*)vdst)[1] = a1;
            ((float4*)vdst)[2] = a2; ((float4*)vdst)[3] = a3;
        }
        __syncthreads();                                    // tile staged

        // ---------------- A phase ----------------
        float lg0[4] = {0.f,0.f,0.f,0.f}, lg1[4] = {0.f,0.f,0.f,0.f};
#pragma unroll
        for (int d = 0; d < 16; d++) {
            float4 k4 = *(const float4*)&kt[d][4 * aS];
            lg0[0] += qa[d]  * k4.x; lg0[1] += qa[d]  * k4.y;
            lg0[2] += qa[d]  * k4.z; lg0[3] += qa[d]  * k4.w;
            lg1[0] += qb_[d] * k4.x; lg1[1] += qb_[d] * k4.y;
            lg1[2] += qb_[d] * k4.z; lg1[3] += qb_[d] * k4.w;
        }
#pragma unroll
        for (int u = 0; u < 4; u++) {
            int m = m0 + 4 * aS + u;
            int mc = m < N3 ? m : 0;
            int mx = mc / R2; int mrem = mc - mx * R2; int my = mrem / R_;
            float bi0 = ab[iabs(nx0 - mx) * R_ + iabs(ny0 - my)];
            float bi1 = ab[iabs(nx1 - mx) * R_ + iabs(ny1 - my)];
            bool ok = m < N3;
            lg0[u] = ok ? 0.25f * lg0[u] + bi0 : -3.0e38f;
            lg1[u] = ok ? 0.25f * lg1[u] + bi1 : -3.0e38f;
        }
        float tm0 = fmaxf(fmaxf(lg0[0], lg0[1]), fmaxf(lg0[2], lg0[3]));
        float tm1 = fmaxf(fmaxf(lg1[0], lg1[1]), fmaxf(lg1[2], lg1[3]));
#pragma unroll
        for (int mk = 1; mk < 16; mk <<= 1) {
            tm0 = fmaxf(tm0, __shfl_xor(tm0, mk));
            tm1 = fmaxf(tm1, __shfl_xor(tm1, mk));
        }
        float fr0 = 1.f, fr1 = 1.f;
        if (tm0 > mr0 + 8.f) { fr0 = __expf(mr0 - tm0); mr0 = tm0; lp0 *= fr0; }
        if (tm1 > mr1 + 8.f) { fr1 = __expf(mr1 - tm1); mr1 = tm1; lp1 *= fr1; }
#pragma unroll
        for (int u = 0; u < 4; u++) {
            float w0 = __expf(lg0[u] - mr0);
            float w1 = __expf(lg1[u] - mr1);
            lp0 += w0; lp1 += w1;
            wt[4 * aS + u][aP]      = w0;
            wt[4 * aS + u][aP + 16] = w1;
        }
        if (aS == 0) { fra[aP] = fr0; fra[aP + 16] = fr1; }
        __syncthreads();                                    // w visible

        // ---------------- B phase ----------------
        {
            float4 fa = *(const float4*)&fra[8 * bP];
            float4 fb = *(const float4*)&fra[8 * bP + 4];
            if (__any(fa.x != 1.f || fa.y != 1.f || fa.z != 1.f || fa.w != 1.f ||
                      fb.x != 1.f || fb.y != 1.f || fb.z != 1.f || fb.w != 1.f)) {
                float fr[8] = {fa.x, fa.y, fa.z, fa.w, fb.x, fb.y, fb.z, fb.w};
#pragma unroll
                for (int r = 0; r < 8; r++)
#pragma unroll
                    for (int e = 0; e < 8; e++) acc[r][e] *= fr[r];
            }
        }
#pragma unroll
        for (int j = 0; j < 4; j++) {
            int m2 = 2 * bS + 16 * j;
            float4 wA0 = *(const float4*)&wt[m2][8 * bP];
            float4 wA1 = *(const float4*)&wt[m2][8 * bP + 4];
            float4 wB0 = *(const float4*)&wt[m2 + 1][8 * bP];
            float4 wB1 = *(const float4*)&wt[m2 + 1][8 * bP + 4];
            float w0[8] = {wA0.x, wA0.y, wA0.z, wA0.w, wA1.x, wA1.y, wA1.z, wA1.w};
            float w1[8] = {wB0.x, wB0.y, wB0.z, wB0.w, wB1.x, wB1.y, wB1.z, wB1.w};
#pragma unroll
            for (int e = 0; e < 8; e++) {
                float2 v2 = *(const float2*)&vt[8 * bC + e][m2];
#pragma unroll
                for (int r = 0; r < 8; r++)
                    acc[r][e] += w0[r] * v2.x + w1[r] * v2.y;
            }
        }
    }

    // ---------------- epilogue ----------------
#pragma unroll
    for (int mk = 1; mk < 16; mk <<= 1) {
        lp0 += __shfl_xor(lp0, mk);
        lp1 += __shfl_xor(lp1, mk);
    }
    if (aS == 0) { linv[aP] = 1.f / lp0; linv[aP + 16] = 1.f / lp1; }
    __syncthreads();   // linv visible; all vt reads done

    // reduce acc over bS (m-slices)
#pragma unroll
    for (int mk = 1; mk < 8; mk <<= 1) {
#pragma unroll
        for (int r = 0; r < 8; r++)
#pragma unroll
            for (int e = 0; e < 8; e++)
                acc[r][e] += __shfl_xor(acc[r][e], mk);
    }
    {
        float4 la = *(const float4*)&linv[8 * bP];
        float4 lb = *(const float4*)&linv[8 * bP + 4];
        float li[8] = {la.x, la.y, la.z, la.w, lb.x, lb.y, lb.z, lb.w};
#pragma unroll
        for (int r = 0; r < 8; r++)
#pragma unroll
            for (int e = 0; e < 8; e++) acc[r][e] *= li[r];
    }
    if (bS == 0) {
#pragma unroll
        for (int i = 0; i < 8; i++) {
            *(float4*)&vt[8 * bP + i][8 * bC]     = make_float4(acc[i][0], acc[i][1], acc[i][2], acc[i][3]);
            *(float4*)&vt[8 * bP + i][8 * bC + 4] = make_float4(acc[i][4], acc[i][5], acc[i][6], acc[i][7]);
        }
    }
    __syncthreads();
    float* hb = h + ((size_t)b * C_ + head * DV) * N3;
#pragma unroll
    for (int i = 0; i < 8; i++) {
        int f = t + 256 * i;
        int n = f & 31, ch = f >> 5;
        int row = qbase + n;
        if (row < N3) hb[(size_t)ch * N3 + row] = vt[n][ch];
    }
}

// ---------------------------------------------------------------------------
// Projection: out[o,n] = psc[o]*sum_c Wp[o,c]*relu(h[c,n]) + pbi[o]
// grid (98, B), block 128; float4-blocked LDS reads
// ---------------------------------------------------------------------------
__global__ __launch_bounds__(128)
void proj_kernel(const float* __restrict__ h, const float* __restrict__ Wp,
                 const float* __restrict__ psc, const float* __restrict__ pbi,
                 float* __restrict__ out)
{
    __shared__ float ht[256][28];
    int b = blockIdx.y; int n0 = blockIdx.x * 28; int t = threadIdx.x;

    const float* hb = h + (size_t)b * C_ * N3 + n0;
    for (int i = t; i < 256 * 28; i += 128) {
        int c = i / 28; int j = i - c * 28;
        float v = hb[(size_t)c * N3 + j];
        ht[c][j] = v > 0.f ? v : 0.f;
    }
    __syncthreads();

    int o0 = t, o1 = t + 128;
    float4 a0[7], a1[7];
#pragma unroll
    for (int jb = 0; jb < 7; jb++) { a0[jb] = make_float4(0,0,0,0); a1[jb] = make_float4(0,0,0,0); }

    const float4* w04 = (const float4*)(Wp + (size_t)o0 * 256);
    const float4* w14 = (const float4*)(Wp + (size_t)o1 * 256);
    for (int c4 = 0; c4 < 64; c4++) {
        float4 wa = w04[c4], wb = w14[c4];
        int cb = c4 * 4;
#pragma unroll
        for (int u = 0; u < 4; u++) {
            float W0 = (u == 0) ? wa.x : (u == 1) ? wa.y : (u == 2) ? wa.z : wa.w;
            float W1 = (u == 0) ? wb.x : (u == 1) ? wb.y : (u == 2) ? wb.z : wb.w;
#pragma unroll
            for (int jb = 0; jb < 7; jb++) {
                float4 hv = *(const float4*)&ht[cb + u][4 * jb];
                a0[jb].x += W0 * hv.x; a0[jb].y += W0 * hv.y;
                a0[jb].z += W0 * hv.z; a0[jb].w += W0 * hv.w;
                a1[jb].x += W1 * hv.x; a1[jb].y += W1 * hv.y;
                a1[jb].z += W1 * hv.z; a1[jb].w += W1 * hv.w;
            }
        }
    }

    float s0 = psc[o0], b0 = pbi[o0], s1 = psc[o1], b1 = pbi[o1];
    float* ob0 = out + ((size_t)b * C_ + o0) * N3 + n0;
    float* ob1 = out + ((size_t)b * C_ + o1) * N3 + n0;
#pragma unroll
    for (int jb = 0; jb < 7; jb++) {
        float4 r0 = make_float4(a0[jb].x * s0 + b0, a0[jb].y * s0 + b0,
                                a0[jb].z * s0 + b0, a0[jb].w * s0 + b0);
        float4 r1 = make_float4(a1[jb].x * s1 + b1, a1[jb].y * s1 + b1,
                                a1[jb].z * s1 + b1, a1[jb].w * s1 + b1);
        *(float4*)&ob0[4 * jb] = r0;
        *(float4*)&ob1[4 * jb] = r1;
    }
}

// ---------------------------------------------------------------------------
extern "C" void kernel_launch(void* const* d_in, const int* in_sizes, int n_in,
                              void* d_out, int out_size, void* d_ws, size_t ws_size,
                              hipStream_t stream)
{
    const float* x    = (const float*)d_in[0];
    const float* Wqkv = (const float*)d_in[1];
    const float* qsc  = (const float*)d_in[2];
    const float* qbi  = (const float*)d_in[3];
    const float* Wdw  = (const float*)d_in[4];
    const float* dsc  = (const float*)d_in[5];
    const float* dbi  = (const float*)d_in[6];
    const float* Wp   = (const float*)d_in[7];
    const float* psc  = (const float*)d_in[8];
    const float* pbi  = (const float*)d_in[9];
    const float* ab   = (const float*)d_in[10];
    // d_in[11] = bias_idx: unused (computed analytically)

    float* out = (float*)d_out;
    float* ws  = (float*)d_ws;
    float* q0 = ws;                                   // B*KD*NP
    float* kb = q0 + (size_t)B_ * KD * NP;            // B*KD*NP
    float* vb = kb + (size_t)B_ * KD * NP;            // B*DV*NP
    float* h  = vb + (size_t)B_ * DV * NP;            // B*C_*N3 (pre-relu)

    for (int head = 0; head < NH; head++) {
        qkv_kernel<<<dim3(11, B_, 4), 256, 0, stream>>>(x, h, Wqkv, qsc, qbi, q0, kb, vb, head);
        dwconv_kernel<<<dim3(KD, B_), 256, 0, stream>>>(q0, Wdw, dsc, dbi, head);
        attn_kernel<<<dim3(86, B_), 256, 0, stream>>>(q0, kb, vb, h, ab, head);
    }
    proj_kernel<<<dim3(98, B_), 128, 0, stream>>>(h, Wp, psc, pbi, out);
}

// Round 4
// 2389.547 us; speedup vs baseline: 5.0031x; 2.1605x over previous
//
#include <hip/hip_runtime.h>

#define B_    8
#define C_    256
#define R_    14
#define R2    196
#define N3    2744     // 14^3
#define NP    2752     // padded (43*64): guard-free tile staging
#define NH    4
#define KD    16
#define DV    64
#define QKVO  96       // 2*KD + DV
#define MT    64       // m-tile in attention
#define NTILE 43
#define SPLIT 4
#define TPC   11       // tiles per m-chunk (last chunk gets 10)

__device__ __forceinline__ int iabs(int v){ return v < 0 ? -v : v; }

// ---------------------------------------------------------------------------
// QKV: y[o,n] = sum_c W[o,c] * feat[c,n]; feat = x_chunk (+ prev attn out)
// grid (11, B, 4), block 256
// ---------------------------------------------------------------------------
__global__ __launch_bounds__(256)
void qkv_kernel(const float* __restrict__ x, const float* __restrict__ h,
                const float* __restrict__ W, const float* __restrict__ sc,
                const float* __restrict__ bi,
                float* __restrict__ q0, float* __restrict__ kb, float* __restrict__ vb,
                int head)
{
    int b = blockIdx.y;
    int og = blockIdx.z;
    int n = blockIdx.x * 256 + threadIdx.x;
    if (n >= N3) return;

    float f[64];
    const float* xb = x + ((size_t)b * C_ + head * DV) * N3 + n;
    if (head == 0) {
#pragma unroll
        for (int c = 0; c < 64; c++) f[c] = xb[(size_t)c * N3];
    } else {
        const float* hb = h + ((size_t)b * C_ + (head - 1) * DV) * N3 + n;
#pragma unroll
        for (int c = 0; c < 64; c++) f[c] = xb[(size_t)c * N3] + hb[(size_t)c * N3];
    }

    const float* Wh  = W  + head * QKVO * 64;   // uniform -> s_loads
    const float* sch = sc + head * QKVO;
    const float* bih = bi + head * QKVO;

    float* qo = q0 + (size_t)b * KD * NP + n;
    float* ko = kb + (size_t)b * KD * NP + n;
    float* vo = vb + (size_t)b * DV * NP + n;

    for (int oo = 0; oo < 24; oo++) {
        int o = og * 24 + oo;
        float acc = 0.f;
#pragma unroll
        for (int c = 0; c < 64; c++) acc += Wh[o * 64 + c] * f[c];
        acc = acc * sch[o] + bih[o];
        if (o < KD)            qo[(size_t)o * NP] = acc;
        else if (o < 2 * KD)   ko[(size_t)(o - KD) * NP] = acc;
        else                   vo[(size_t)(o - 2 * KD) * NP] = acc;
    }
}

// ---------------------------------------------------------------------------
// Depthwise 5x5x5 SAME conv on q (stride NP), + scale/bias
// grid (KD, B), block 256
// ---------------------------------------------------------------------------
__global__ __launch_bounds__(256)
void dwconv_kernel(float* __restrict__ q0, const float* __restrict__ Wdw,
                   const float* __restrict__ dsc, const float* __restrict__ dbi,
                   int head)
{
    __shared__ float ch[N3];
    int b = blockIdx.y, c = blockIdx.x;
    int t = threadIdx.x;
    float* qc = q0 + ((size_t)b * KD + c) * NP;
    for (int i = t; i < N3; i += 256) ch[i] = qc[i];
    __syncthreads();

    const float* w = Wdw + (head * KD + c) * 125;
    float scl = dsc[head * KD + c], bia = dbi[head * KD + c];

    for (int i = t; i < N3; i += 256) {
        int xx = i / R2; int rem = i - xx * R2; int yy = rem / R_; int zz = rem - yy * R_;
        float acc = 0.f;
#pragma unroll
        for (int a = 0; a < 5; a++) {
            int xa = xx + a - 2;
            if ((unsigned)xa >= (unsigned)R_) continue;
#pragma unroll
            for (int bb = 0; bb < 5; bb++) {
                int yb = yy + bb - 2;
                if ((unsigned)yb >= (unsigned)R_) continue;
#pragma unroll
                for (int cc = 0; cc < 5; cc++) {
                    int zc = zz + cc - 2;
                    if ((unsigned)zc >= (unsigned)R_) continue;
                    acc += w[a * 25 + bb * 5 + cc] * ch[xa * R2 + yb * R_ + zc];
                }
            }
        }
        qc[i] = acc * scl + bia;
    }
}

// ---------------------------------------------------------------------------
// Attention partial (flash-decoding m-split, no max tracking: |logits| << 88).
// Round-1 thread mapping: 64 q-rows/block, thread = (row-pair p, m-slice s of 8).
// grid (43, B, SPLIT), block 256. Writes unnormalized (acc, l) partials.
// ---------------------------------------------------------------------------
__global__ __launch_bounds__(256)
void attn_partial(const float* __restrict__ q0, const float* __restrict__ kb,
                  const float* __restrict__ vb, float* __restrict__ pacc,
                  float* __restrict__ pl, const float* __restrict__ abias, int head)
{
    __shared__ float kt[MT][20];     // [m][d], stride 20
    __shared__ float vt[MT][68];     // [m][c], stride 68
    __shared__ int   mxa[MT];
    __shared__ int   mya[MT];
    __shared__ float ab[R2];

    const int b = blockIdx.y, z = blockIdx.z;
    const int qbase = blockIdx.x * 64;
    const int t = threadIdx.x;
    const int s = t & 7;            // m-slice
    const int p = t >> 3;           // row-pair [0,32)
    const int rA = qbase + p;       // always < N3 (max 2719)
    const int rB = rA + 32;
    const bool vB_ = rB < N3;

    if (t < R2) ab[t] = abias[head * R2 + t];

    const float* qq = q0 + (size_t)b * KD * NP;
    float qA[KD], qB[KD];
#pragma unroll
    for (int d = 0; d < KD; d++) {
        qA[d] = qq[(size_t)d * NP + rA];
        qB[d] = qq[(size_t)d * NP + rB];   // rB<NP; padded rows hold finite junk, outputs guarded
    }
    int nxA = rA / R2, nyA = (rA - nxA * R2) / R_;
    int rc  = vB_ ? rB : 0;
    int nxB = rc / R2, nyB = (rc - nxB * R2) / R_;

    float lA = 0.f, lB = 0.f;
    float4 aA[16], aB[16];
#pragma unroll
    for (int r = 0; r < 16; r++) { aA[r] = make_float4(0,0,0,0); aB[r] = make_float4(0,0,0,0); }

    const float* kg = kb + (size_t)b * KD * NP;
    const float* vg = vb + (size_t)b * DV * NP;

    const int tEnd = min(z * TPC + TPC, NTILE);
    for (int t0 = z * TPC; t0 < tEnd; t0++) {
        const int m0 = t0 * MT;
        __syncthreads();
        for (int i = t; i < MT * KD; i += 256) {
            int mm = i & 63, d = i >> 6;
            kt[mm][d] = kg[(size_t)d * NP + m0 + mm];
        }
        for (int i = t; i < MT * DV; i += 256) {
            int mm = i & 63, c = i >> 6;
            vt[mm][c] = vg[(size_t)c * NP + m0 + mm];
        }
        if (t < MT) {
            int m = m0 + t;
            int mc = m < N3 ? m : 0;
            int mx = mc / R2; int rem = mc - mx * R2;
            mxa[t] = mx; mya[t] = rem / R_;
        }
        __syncthreads();

        const int mvalid = N3 - m0;   // >= 56 even on the last tile
#pragma unroll
        for (int j = 0; j < 8; j++) {
            int mm = s + j * 8;
            float kk[16];
            *(float4*)&kk[0]  = *(const float4*)&kt[mm][0];
            *(float4*)&kk[4]  = *(const float4*)&kt[mm][4];
            *(float4*)&kk[8]  = *(const float4*)&kt[mm][8];
            *(float4*)&kk[12] = *(const float4*)&kt[mm][12];
            float dA = 0.f, dB = 0.f;
#pragma unroll
            for (int d = 0; d < 16; d++) { dA += qA[d] * kk[d]; dB += qB[d] * kk[d]; }
            int mx = mxa[mm], my = mya[mm];
            float lgA = 0.25f * dA + ab[iabs(nxA - mx) * R_ + iabs(nyA - my)];
            float lgB = 0.25f * dB + ab[iabs(nxB - mx) * R_ + iabs(nyB - my)];
            bool ok = mm < mvalid;
            float wA = ok ? __expf(lgA) : 0.f;
            float wB = ok ? __expf(lgB) : 0.f;
            lA += wA; lB += wB;
#pragma unroll
            for (int r = 0; r < 16; r++) {
                float4 vv = *(const float4*)&vt[mm][r * 4];
                aA[r].x += wA * vv.x; aA[r].y += wA * vv.y;
                aA[r].z += wA * vv.z; aA[r].w += wA * vv.w;
                aB[r].x += wB * vv.x; aB[r].y += wB * vv.y;
                aB[r].z += wB * vv.z; aB[r].w += wB * vv.w;
            }
        }
    }

    // plain butterfly sum across the 8 m-slices (lane bits 0..2)
#pragma unroll
    for (int mk = 1; mk < 8; mk <<= 1) {
        lA += __shfl_xor(lA, mk);
        lB += __shfl_xor(lB, mk);
#pragma unroll
        for (int r = 0; r < 16; r++) {
            aA[r].x += __shfl_xor(aA[r].x, mk);
            aA[r].y += __shfl_xor(aA[r].y, mk);
            aA[r].z += __shfl_xor(aA[r].z, mk);
            aA[r].w += __shfl_xor(aA[r].w, mk);
            aB[r].x += __shfl_xor(aB[r].x, mk);
            aB[r].y += __shfl_xor(aB[r].y, mk);
            aB[r].z += __shfl_xor(aB[r].z, mk);
            aB[r].w += __shfl_xor(aB[r].w, mk);
        }
    }

    float* pbase = pacc + (size_t)(b * SPLIT + z) * DV * NP;
    if (s == 0) {
        pl[(size_t)(b * SPLIT + z) * NP + rA] = lA;
        if (vB_) pl[(size_t)(b * SPLIT + z) * NP + rB] = lB;
    }
#pragma unroll
    for (int r = 0; r < 16; r++) {
        if ((r >> 1) == s) {   // slice s owns rows r = 2s, 2s+1 of acc
            pbase[(size_t)(r*4+0) * NP + rA] = aA[r].x;
            pbase[(size_t)(r*4+1) * NP + rA] = aA[r].y;
            pbase[(size_t)(r*4+2) * NP + rA] = aA[r].z;
            pbase[(size_t)(r*4+3) * NP + rA] = aA[r].w;
            if (vB_) {
                pbase[(size_t)(r*4+0) * NP + rB] = aB[r].x;
                pbase[(size_t)(r*4+1) * NP + rB] = aB[r].y;
                pbase[(size_t)(r*4+2) * NP + rB] = aB[r].z;
                pbase[(size_t)(r*4+3) * NP + rB] = aB[r].w;
            }
        }
    }
}

// ---------------------------------------------------------------------------
// Combine SPLIT partials: h = (sum_z acc_z) / (sum_z l_z)
// grid (11, B), block 256
// ---------------------------------------------------------------------------
__global__ __launch_bounds__(256)
void attn_combine(const float* __restrict__ pacc, const float* __restrict__ pl,
                  float* __restrict__ h, int head)
{
    int b = blockIdx.y;
    int r = blockIdx.x * 256 + threadIdx.x;
    if (r >= N3) return;
    float l = 0.f;
#pragma unroll
    for (int z = 0; z < SPLIT; z++) l += pl[(size_t)(b * SPLIT + z) * NP + r];
    float inv = 1.f / l;
    float* hb = h + ((size_t)b * C_ + head * DV) * N3 + r;
    const float* pb = pacc + (size_t)b * SPLIT * DV * NP + r;
#pragma unroll
    for (int ch = 0; ch < DV; ch++) {
        float a = 0.f;
#pragma unroll
        for (int z = 0; z < SPLIT; z++) a += pb[(size_t)(z * DV + ch) * NP];
        hb[(size_t)ch * N3] = a * inv;
    }
}

// ---------------------------------------------------------------------------
// Projection: out[o,n] = psc[o]*sum_c Wp[o,c]*relu(h[c,n]) + pbi[o]
// grid (98, B), block 128
// ---------------------------------------------------------------------------
__global__ __launch_bounds__(128)
void proj_kernel(const float* __restrict__ h, const float* __restrict__ Wp,
                 const float* __restrict__ psc, const float* __restrict__ pbi,
                 float* __restrict__ out)
{
    __shared__ float ht[256][28];
    int b = blockIdx.y; int n0 = blockIdx.x * 28; int t = threadIdx.x;

    const float* hb = h + (size_t)b * C_ * N3 + n0;
    for (int i = t; i < 256 * 28; i += 128) {
        int c = i / 28; int j = i - c * 28;
        float v = hb[(size_t)c * N3 + j];
        ht[c][j] = v > 0.f ? v : 0.f;
    }
    __syncthreads();

    int o0 = t, o1 = t + 128;
    float4 a0[7], a1[7];
#pragma unroll
    for (int jb = 0; jb < 7; jb++) { a0[jb] = make_float4(0,0,0,0); a1[jb] = make_float4(0,0,0,0); }

    const float4* w04 = (const float4*)(Wp + (size_t)o0 * 256);
    const float4* w14 = (const float4*)(Wp + (size_t)o1 * 256);
    for (int c4 = 0; c4 < 64; c4++) {
        float4 wa = w04[c4], wb = w14[c4];
        int cb = c4 * 4;
#pragma unroll
        for (int u = 0; u < 4; u++) {
            float W0 = (u == 0) ? wa.x : (u == 1) ? wa.y : (u == 2) ? wa.z : wa.w;
            float W1 = (u == 0) ? wb.x : (u == 1) ? wb.y : (u == 2) ? wb.z : wb.w;
#pragma unroll
            for (int jb = 0; jb < 7; jb++) {
                float4 hv = *(const float4*)&ht[cb + u][4 * jb];
                a0[jb].x += W0 * hv.x; a0[jb].y += W0 * hv.y;
                a0[jb].z += W0 * hv.z; a0[jb].w += W0 * hv.w;
                a1[jb].x += W1 * hv.x; a1[jb].y += W1 * hv.y;
                a1[jb].z += W1 * hv.z; a1[jb].w += W1 * hv.w;
            }
        }
    }

    float s0 = psc[o0], b0 = pbi[o0], s1 = psc[o1], b1 = pbi[o1];
    float* ob0 = out + ((size_t)b * C_ + o0) * N3 + n0;
    float* ob1 = out + ((size_t)b * C_ + o1) * N3 + n0;
#pragma unroll
    for (int jb = 0; jb < 7; jb++) {
        float4 r0 = make_float4(a0[jb].x * s0 + b0, a0[jb].y * s0 + b0,
                                a0[jb].z * s0 + b0, a0[jb].w * s0 + b0);
        float4 r1 = make_float4(a1[jb].x * s1 + b1, a1[jb].y * s1 + b1,
                                a1[jb].z * s1 + b1, a1[jb].w * s1 + b1);
        *(float4*)&ob0[4 * jb] = r0;
        *(float4*)&ob1[4 * jb] = r1;
    }
}

// ---------------------------------------------------------------------------
extern "C" void kernel_launch(void* const* d_in, const int* in_sizes, int n_in,
                              void* d_out, int out_size, void* d_ws, size_t ws_size,
                              hipStream_t stream)
{
    const float* x    = (const float*)d_in[0];
    const float* Wqkv = (const float*)d_in[1];
    const float* qsc  = (const float*)d_in[2];
    const float* qbi  = (const float*)d_in[3];
    const float* Wdw  = (const float*)d_in[4];
    const float* dsc  = (const float*)d_in[5];
    const float* dbi  = (const float*)d_in[6];
    const float* Wp   = (const float*)d_in[7];
    const float* psc  = (const float*)d_in[8];
    const float* pbi  = (const float*)d_in[9];
    const float* ab   = (const float*)d_in[10];
    // d_in[11] = bias_idx: unused (computed analytically)

    float* out = (float*)d_out;
    float* ws  = (float*)d_ws;
    float* q0   = ws;                                     // B*KD*NP
    float* kb   = q0 + (size_t)B_ * KD * NP;              // B*KD*NP
    float* vb   = kb + (size_t)B_ * KD * NP;              // B*DV*NP
    float* h    = vb + (size_t)B_ * DV * NP;              // B*C_*N3
    float* pacc = h  + (size_t)B_ * C_ * N3;              // B*SPLIT*DV*NP
    float* pl   = pacc + (size_t)B_ * SPLIT * DV * NP;    // B*SPLIT*NP

    for (int head = 0; head < NH; head++) {
        qkv_kernel<<<dim3(11, B_, 4), 256, 0, stream>>>(x, h, Wqkv, qsc, qbi, q0, kb, vb, head);
        dwconv_kernel<<<dim3(KD, B_), 256, 0, stream>>>(q0, Wdw, dsc, dbi, head);
        attn_partial<<<dim3(43, B_, SPLIT), 256, 0, stream>>>(q0, kb, vb, pacc, pl, ab, head);
        attn_combine<<<dim3(11, B_), 256, 0, stream>>>(pacc, pl, h, head);
    }
    proj_kernel<<<dim3(98, B_), 128, 0, stream>>>(h, Wp, psc, pbi, out);
}

// Round 5
// 744.673 us; speedup vs baseline: 16.0541x; 3.2089x over previous
//
#include <hip/hip_runtime.h>

#define B_    8
#define C_    256
#define R_    14
#define R2    196
#define N3    2744     // 14^3
#define NP    2752     // padded (43*64): guard-free tile staging
#define NH    4
#define KD    16
#define DV    64
#define QKVO  96       // 2*KD + DV
#define MT    64       // m-tile in attention
#define NTILE 43
#define SPLIT 4
#define TPC   11       // tiles per m-chunk

typedef __attribute__((ext_vector_type(8))) short short8v;
typedef __attribute__((ext_vector_type(4))) short short4v;
typedef __attribute__((ext_vector_type(4))) float float4v;

__device__ __forceinline__ int iabs(int v){ return v < 0 ? -v : v; }

// fp32 -> bf16 round-to-nearest-even (finite inputs)
__device__ __forceinline__ short f2bf(float f){
    union { float f; unsigned int u; } c; c.f = f;
    return (short)((c.u + 0x7FFFu + ((c.u >> 16) & 1u)) >> 16);
}

// ---------------------------------------------------------------------------
// QKV: y[o,n] = sum_c W[o,c] * feat[c,n]; feat = x_chunk (+ prev attn out)
// grid (11, B, 4), block 256
// ---------------------------------------------------------------------------
__global__ __launch_bounds__(256)
void qkv_kernel(const float* __restrict__ x, const float* __restrict__ h,
                const float* __restrict__ W, const float* __restrict__ sc,
                const float* __restrict__ bi,
                float* __restrict__ q0, float* __restrict__ kb, float* __restrict__ vb,
                int head)
{
    int b = blockIdx.y;
    int og = blockIdx.z;
    int n = blockIdx.x * 256 + threadIdx.x;
    if (n >= N3) return;

    float f[64];
    const float* xb = x + ((size_t)b * C_ + head * DV) * N3 + n;
    if (head == 0) {
#pragma unroll
        for (int c = 0; c < 64; c++) f[c] = xb[(size_t)c * N3];
    } else {
        const float* hb = h + ((size_t)b * C_ + (head - 1) * DV) * N3 + n;
#pragma unroll
        for (int c = 0; c < 64; c++) f[c] = xb[(size_t)c * N3] + hb[(size_t)c * N3];
    }

    const float* Wh  = W  + head * QKVO * 64;   // uniform -> s_loads
    const float* sch = sc + head * QKVO;
    const float* bih = bi + head * QKVO;

    float* qo = q0 + (size_t)b * KD * NP + n;
    float* ko = kb + (size_t)b * KD * NP + n;
    float* vo = vb + (size_t)b * DV * NP + n;

    for (int oo = 0; oo < 24; oo++) {
        int o = og * 24 + oo;
        float acc = 0.f;
#pragma unroll
        for (int c = 0; c < 64; c++) acc += Wh[o * 64 + c] * f[c];
        acc = acc * sch[o] + bih[o];
        if (o < KD)            qo[(size_t)o * NP] = acc;
        else if (o < 2 * KD)   ko[(size_t)(o - KD) * NP] = acc;
        else                   vo[(size_t)(o - 2 * KD) * NP] = acc;
    }
}

// ---------------------------------------------------------------------------
// Depthwise 5x5x5 SAME conv on q (stride NP), + scale/bias
// grid (KD, B), block 256
// ---------------------------------------------------------------------------
__global__ __launch_bounds__(256)
void dwconv_kernel(float* __restrict__ q0, const float* __restrict__ Wdw,
                   const float* __restrict__ dsc, const float* __restrict__ dbi,
                   int head)
{
    __shared__ float ch[N3];
    int b = blockIdx.y, c = blockIdx.x;
    int t = threadIdx.x;
    float* qc = q0 + ((size_t)b * KD + c) * NP;
    for (int i = t; i < N3; i += 256) ch[i] = qc[i];
    __syncthreads();

    const float* w = Wdw + (head * KD + c) * 125;
    float scl = dsc[head * KD + c], bia = dbi[head * KD + c];

    for (int i = t; i < N3; i += 256) {
        int xx = i / R2; int rem = i - xx * R2; int yy = rem / R_; int zz = rem - yy * R_;
        float acc = 0.f;
#pragma unroll
        for (int a = 0; a < 5; a++) {
            int xa = xx + a - 2;
            if ((unsigned)xa >= (unsigned)R_) continue;
#pragma unroll
            for (int bb = 0; bb < 5; bb++) {
                int yb = yy + bb - 2;
                if ((unsigned)yb >= (unsigned)R_) continue;
#pragma unroll
                for (int cc = 0; cc < 5; cc++) {
                    int zc = zz + cc - 2;
                    if ((unsigned)zc >= (unsigned)R_) continue;
                    acc += w[a * 25 + bb * 5 + cc] * ch[xa * R2 + yb * R_ + zc];
                }
            }
        }
        qc[i] = acc * scl + bia;
    }
}

// ---------------------------------------------------------------------------
// Attention partial v5: bf16 MFMA (16x16x32). 64 q-rows/block, 4 waves, each
// wave owns 16 n's. QK^T: D=S^T tiles via A=K^T (zero-padded K=32), B=Q.
// Softmax fp32 (plain exp, no max). P->bf16 via per-wave p_lds. PV: A=P, B=V.
// grid (43, B, SPLIT), block 256. Unnormalized (acc, l) partials.
// ---------------------------------------------------------------------------
__global__ __launch_bounds__(256, 3)
void attn_partial(const float* __restrict__ q0, const float* __restrict__ kb,
                  const float* __restrict__ vb, float* __restrict__ pacc,
                  float* __restrict__ pl, const float* __restrict__ abias, int head)
{
    __shared__ short ktT[64][40];      // [m][d], d 0..15 real, 16..31 zeros, pad->40
    __shared__ short vtT[64][72];      // [c][m], pad 72
    __shared__ short plds[4][16][72];  // per-wave P [n][m]
    __shared__ int   mxa[64];          // packed (mx<<8)|my per m
    __shared__ float ab[196];

    const int b = blockIdx.y, z = blockIdx.z;
    const int qbase = blockIdx.x * 64;
    const int t = threadIdx.x;
    const int w = t >> 6;        // wave id
    const int l = t & 63;        // lane
    const int g = l >> 4;        // k-group (0..3)
    const int ln = l & 15;       // fragment M/N index

    if (t < 196) ab[t] = abias[head * R2 + t];

    const float* qq = q0 + (size_t)b * KD * NP;
    const float* kg = kb + (size_t)b * KD * NP;
    const float* vg = vb + (size_t)b * DV * NP;

    // zero-fill ktT d=16..31 (once; in-loop staging only writes d<16)
    {
        int mm = t & 63, dg = t >> 6;
        short4v zz = {0, 0, 0, 0};
        *(short4v*)&ktT[mm][16 + dg * 4] = zz;
    }

    // Q B-frag preload: B[k=d][n], lane: n = ln, k = g*8+j (zero for d>=16)
    const int n_my = qbase + w * 16 + ln;    // < NP always
    short8v qf;
#pragma unroll
    for (int j = 0; j < 8; j++) {
        int d = g * 8 + j;
        qf[j] = (d < KD) ? f2bf(qq[(size_t)d * NP + n_my]) : (short)0;
    }
    const int nmc = n_my < N3 ? n_my : 0;
    const int nx = nmc / R2, ny = (nmc - nx * R2) / R_;

    float4v acc[4];
#pragma unroll
    for (int cs = 0; cs < 4; cs++) acc[cs] = (float4v){0.f, 0.f, 0.f, 0.f};
    float lsum = 0.f;

    const int tEnd = min(z * TPC + TPC, NTILE);
    for (int t0 = z * TPC; t0 < tEnd; t0++) {
        const int m0 = t0 * MT;
        __syncthreads();                         // prev tile consumed
        {   // stage K^T: thread (mm = t&63, dg = t>>6) -> ktT[mm][dg*4..+3]
            int mm = t & 63, dg = t >> 6;
            short4v kv;
#pragma unroll
            for (int i2 = 0; i2 < 4; i2++)
                kv[i2] = f2bf(kg[(size_t)(dg * 4 + i2) * NP + m0 + mm]);
            *(short4v*)&ktT[mm][dg * 4] = kv;
        }
        {   // stage V: thread (c = t>>2, mq = t&3) -> vtT[c][mq*16..+15]
            int c = t >> 2, mq = t & 3;
            const float* vs = vg + (size_t)c * NP + m0 + mq * 16;
            float4 f0 = ((const float4*)vs)[0];
            float4 f1 = ((const float4*)vs)[1];
            float4 f2 = ((const float4*)vs)[2];
            float4 f3 = ((const float4*)vs)[3];
            short8v s0 = { f2bf(f0.x), f2bf(f0.y), f2bf(f0.z), f2bf(f0.w),
                           f2bf(f1.x), f2bf(f1.y), f2bf(f1.z), f2bf(f1.w) };
            short8v s1 = { f2bf(f2.x), f2bf(f2.y), f2bf(f2.z), f2bf(f2.w),
                           f2bf(f3.x), f2bf(f3.y), f2bf(f3.z), f2bf(f3.w) };
            *(short8v*)&vtT[c][mq * 16]     = s0;
            *(short8v*)&vtT[c][mq * 16 + 8] = s1;
        }
        if (t < 64) {
            int m = m0 + t; int mc = m < N3 ? m : 0;
            int mx = mc / R2; int rem = mc - mx * R2; int my = rem / R_;
            mxa[t] = (mx << 8) | my;
        }
        __syncthreads();                         // tile staged

        const int mvalid = N3 - m0;              // >= 56

        // ---- QK^T + softmax, one 16m x 16n subtile at a time ----
#pragma unroll
        for (int ms = 0; ms < 4; ms++) {
            short8v af = *(const short8v*)&ktT[ms * 16 + ln][g * 8];
            float4v zf = {0.f, 0.f, 0.f, 0.f};
            float4v s = __builtin_amdgcn_mfma_f32_16x16x32_bf16(af, qf, zf, 0, 0, 0);
            // lane holds S^T[m = ms*16 + g*4 + r][n = ln]
            int4 pk4 = *(const int4*)&mxa[ms * 16 + g * 4];
            int pka[4] = {pk4.x, pk4.y, pk4.z, pk4.w};
            float p[4];
#pragma unroll
            for (int r = 0; r < 4; r++) {
                int mx = pka[r] >> 8, my = pka[r] & 255;
                float lg = 0.25f * s[r] + ab[iabs(nx - mx) * R_ + iabs(ny - my)];
                int mloc = ms * 16 + g * 4 + r;
                float pe = __expf(lg);
                p[r] = (mloc < mvalid) ? pe : 0.f;
                lsum += p[r];
            }
            short4v pw = { f2bf(p[0]), f2bf(p[1]), f2bf(p[2]), f2bf(p[3]) };
            *(short4v*)&plds[w][ln][ms * 16 + g * 4] = pw;
        }

        // ---- PV: out[n][c] += P[n][m] V[m][c], K=32 chunks ----
#pragma unroll
        for (int ck = 0; ck < 2; ck++) {
            short8v pa = *(const short8v*)&plds[w][ln][ck * 32 + g * 8];
#pragma unroll
            for (int cs = 0; cs < 4; cs++) {
                short8v vf = *(const short8v*)&vtT[cs * 16 + ln][ck * 32 + g * 8];
                acc[cs] = __builtin_amdgcn_mfma_f32_16x16x32_bf16(pa, vf, acc[cs], 0, 0, 0);
            }
        }
    }

    // ---- epilogue ----
    lsum += __shfl_xor(lsum, 16);
    lsum += __shfl_xor(lsum, 32);   // all 4 g-lanes of same ln now hold l[n=ln]

    float* pbase = pacc + (size_t)(b * SPLIT + z) * DV * NP;
    if (l < 16) {
        int n_l = qbase + w * 16 + l;
        if (n_l < N3) pl[(size_t)(b * SPLIT + z) * NP + n_l] = lsum;
    }
    // acc[cs]: lane holds out[n = qbase + w*16 + g*4 + r][c = cs*16 + ln]
    const int n0w = qbase + w * 16 + g * 4;
    if (n0w < N3) {   // N3 % 4 == 0, so whole float4 valid
#pragma unroll
        for (int cs = 0; cs < 4; cs++) {
            int c = cs * 16 + ln;
            *(float4v*)&pbase[(size_t)c * NP + n0w] = acc[cs];
        }
    }
}

// ---------------------------------------------------------------------------
// Combine SPLIT partials: h = (sum_z acc_z) / (sum_z l_z)
// grid (11, B), block 256
// ---------------------------------------------------------------------------
__global__ __launch_bounds__(256)
void attn_combine(const float* __restrict__ pacc, const float* __restrict__ pl,
                  float* __restrict__ h, int head)
{
    int b = blockIdx.y;
    int r = blockIdx.x * 256 + threadIdx.x;
    if (r >= N3) return;
    float l = 0.f;
#pragma unroll
    for (int z = 0; z < SPLIT; z++) l += pl[(size_t)(b * SPLIT + z) * NP + r];
    float inv = 1.f / l;
    float* hb = h + ((size_t)b * C_ + head * DV) * N3 + r;
    const float* pb = pacc + (size_t)b * SPLIT * DV * NP + r;
#pragma unroll
    for (int ch = 0; ch < DV; ch++) {
        float a = 0.f;
#pragma unroll
        for (int z = 0; z < SPLIT; z++) a += pb[(size_t)(z * DV + ch) * NP];
        hb[(size_t)ch * N3] = a * inv;
    }
}

// ---------------------------------------------------------------------------
// Projection: out[o,n] = psc[o]*sum_c Wp[o,c]*relu(h[c,n]) + pbi[o]
// grid (98, B), block 128
// ---------------------------------------------------------------------------
__global__ __launch_bounds__(128)
void proj_kernel(const float* __restrict__ h, const float* __restrict__ Wp,
                 const float* __restrict__ psc, const float* __restrict__ pbi,
                 float* __restrict__ out)
{
    __shared__ float ht[256][28];
    int b = blockIdx.y; int n0 = blockIdx.x * 28; int t = threadIdx.x;

    const float* hb = h + (size_t)b * C_ * N3 + n0;
    for (int i = t; i < 256 * 28; i += 128) {
        int c = i / 28; int j = i - c * 28;
        float v = hb[(size_t)c * N3 + j];
        ht[c][j] = v > 0.f ? v : 0.f;
    }
    __syncthreads();

    int o0 = t, o1 = t + 128;
    float4 a0[7], a1[7];
#pragma unroll
    for (int jb = 0; jb < 7; jb++) { a0[jb] = make_float4(0,0,0,0); a1[jb] = make_float4(0,0,0,0); }

    const float4* w04 = (const float4*)(Wp + (size_t)o0 * 256);
    const float4* w14 = (const float4*)(Wp + (size_t)o1 * 256);
    for (int c4 = 0; c4 < 64; c4++) {
        float4 wa = w04[c4], wb = w14[c4];
        int cb = c4 * 4;
#pragma unroll
        for (int u = 0; u < 4; u++) {
            float W0 = (u == 0) ? wa.x : (u == 1) ? wa.y : (u == 2) ? wa.z : wa.w;
            float W1 = (u == 0) ? wb.x : (u == 1) ? wb.y : (u == 2) ? wb.z : wb.w;
#pragma unroll
            for (int jb = 0; jb < 7; jb++) {
                float4 hv = *(const float4*)&ht[cb + u][4 * jb];
                a0[jb].x += W0 * hv.x; a0[jb].y += W0 * hv.y;
                a0[jb].z += W0 * hv.z; a0[jb].w += W0 * hv.w;
                a1[jb].x += W1 * hv.x; a1[jb].y += W1 * hv.y;
                a1[jb].z += W1 * hv.z; a1[jb].w += W1 * hv.w;
            }
        }
    }

    float s0 = psc[o0], b0 = pbi[o0], s1 = psc[o1], b1 = pbi[o1];
    float* ob0 = out + ((size_t)b * C_ + o0) * N3 + n0;
    float* ob1 = out + ((size_t)b * C_ + o1) * N3 + n0;
#pragma unroll
    for (int jb = 0; jb < 7; jb++) {
        float4 r0 = make_float4(a0[jb].x * s0 + b0, a0[jb].y * s0 + b0,
                                a0[jb].z * s0 + b0, a0[jb].w * s0 + b0);
        float4 r1 = make_float4(a1[jb].x * s1 + b1, a1[jb].y * s1 + b1,
                                a1[jb].z * s1 + b1, a1[jb].w * s1 + b1);
        *(float4*)&ob0[4 * jb] = r0;
        *(float4*)&ob1[4 * jb] = r1;
    }
}

// ---------------------------------------------------------------------------
extern "C" void kernel_launch(void* const* d_in, const int* in_sizes, int n_in,
                              void* d_out, int out_size, void* d_ws, size_t ws_size,
                              hipStream_t stream)
{
    const float* x    = (const float*)d_in[0];
    const float* Wqkv = (const float*)d_in[1];
    const float* qsc  = (const float*)d_in[2];
    const float* qbi  = (const float*)d_in[3];
    const float* Wdw  = (const float*)d_in[4];
    const float* dsc  = (const float*)d_in[5];
    const float* dbi  = (const float*)d_in[6];
    const float* Wp   = (const float*)d_in[7];
    const float* psc  = (const float*)d_in[8];
    const float* pbi  = (const float*)d_in[9];
    const float* ab   = (const float*)d_in[10];
    // d_in[11] = bias_idx: unused (computed analytically)

    float* out = (float*)d_out;
    float* ws  = (float*)d_ws;
    float* q0   = ws;                                     // B*KD*NP
    float* kb   = q0 + (size_t)B_ * KD * NP;              // B*KD*NP
    float* vb   = kb + (size_t)B_ * KD * NP;              // B*DV*NP
    float* h    = vb + (size_t)B_ * DV * NP;              // B*C_*N3
    float* pacc = h  + (size_t)B_ * C_ * N3;              // B*SPLIT*DV*NP
    float* pl   = pacc + (size_t)B_ * SPLIT * DV * NP;    // B*SPLIT*NP

    for (int head = 0; head < NH; head++) {
        qkv_kernel<<<dim3(11, B_, 4), 256, 0, stream>>>(x, h, Wqkv, qsc, qbi, q0, kb, vb, head);
        dwconv_kernel<<<dim3(KD, B_), 256, 0, stream>>>(q0, Wdw, dsc, dbi, head);
        attn_partial<<<dim3(43, B_, SPLIT), 256, 0, stream>>>(q0, kb, vb, pacc, pl, ab, head);
        attn_combine<<<dim3(11, B_), 256, 0, stream>>>(pacc, pl, h, head);
    }
    proj_kernel<<<dim3(98, B_), 128, 0, stream>>>(h, Wp, psc, pbi, out);
}

// Round 6
// 500.978 us; speedup vs baseline: 23.8635x; 1.4864x over previous
//
#include <hip/hip_runtime.h>

#define B_    8
#define C_    256
#define R_    14
#define R2    196
#define N3    2744     // 14^3
#define NP    2752     // padded (43*64): guard-free tile staging
#define NH    4
#define KD    16
#define DV    64
#define QKVO  96       // 2*KD + DV
#define MT    64       // m-tile in attention
#define NTILE 43
#define SPLIT 4
#define TPC   11       // tiles per m-chunk

typedef __attribute__((ext_vector_type(8))) short short8v;
typedef __attribute__((ext_vector_type(4))) short short4v;
typedef __attribute__((ext_vector_type(4))) float float4v;

__device__ __forceinline__ int iabs(int v){ return v < 0 ? -v : v; }

// fp32 -> bf16 round-to-nearest-even (finite inputs)
__device__ __forceinline__ short f2bf(float f){
    union { float f; unsigned int u; } c; c.f = f;
    return (short)((c.u + 0x7FFFu + ((c.u >> 16) & 1u)) >> 16);
}

// ---------------------------------------------------------------------------
// QKV: y[o,n] = sum_c W[o,c] * feat[c,n]; feat = x_chunk (+ prev attn out)
// grid (11, B, 4), block 256
// ---------------------------------------------------------------------------
__global__ __launch_bounds__(256)
void qkv_kernel(const float* __restrict__ x, const float* __restrict__ h,
                const float* __restrict__ W, const float* __restrict__ sc,
                const float* __restrict__ bi,
                float* __restrict__ q0, float* __restrict__ kb, float* __restrict__ vb,
                int head)
{
    int b = blockIdx.y;
    int og = blockIdx.z;
    int n = blockIdx.x * 256 + threadIdx.x;
    if (n >= N3) return;

    float f[64];
    const float* xb = x + ((size_t)b * C_ + head * DV) * N3 + n;
    if (head == 0) {
#pragma unroll
        for (int c = 0; c < 64; c++) f[c] = xb[(size_t)c * N3];
    } else {
        const float* hb = h + ((size_t)b * C_ + (head - 1) * DV) * N3 + n;
#pragma unroll
        for (int c = 0; c < 64; c++) f[c] = xb[(size_t)c * N3] + hb[(size_t)c * N3];
    }

    const float* Wh  = W  + head * QKVO * 64;   // uniform -> s_loads
    const float* sch = sc + head * QKVO;
    const float* bih = bi + head * QKVO;

    float* qo = q0 + (size_t)b * KD * NP + n;
    float* ko = kb + (size_t)b * KD * NP + n;
    float* vo = vb + (size_t)b * DV * NP + n;

    for (int oo = 0; oo < 24; oo++) {
        int o = og * 24 + oo;
        float acc = 0.f;
#pragma unroll
        for (int c = 0; c < 64; c++) acc += Wh[o * 64 + c] * f[c];
        acc = acc * sch[o] + bih[o];
        if (o < KD)            qo[(size_t)o * NP] = acc;
        else if (o < 2 * KD)   ko[(size_t)(o - KD) * NP] = acc;
        else                   vo[(size_t)(o - 2 * KD) * NP] = acc;
    }
}

// ---------------------------------------------------------------------------
// Depthwise 5x5x5 SAME conv v6: zero-padded 18^3 LDS volume (branchless; the
// zero halo replicates 'SAME' zero padding), thread = (x,y), z-column in regs.
// Per (dx,dy) tap: one 18-float column read, reused across 5 dz x 14 z.
// grid (KD, B), block 256
// ---------------------------------------------------------------------------
__global__ __launch_bounds__(256)
void dwconv_kernel(float* __restrict__ q0, const float* __restrict__ Wdw,
                   const float* __restrict__ dsc, const float* __restrict__ dbi,
                   int head)
{
    __shared__ float pv[18 * 18 * 18];   // 23.3 KB, [x][y][z] padded +2 halo
    int b = blockIdx.y, c = blockIdx.x;
    int t = threadIdx.x;
    float* qc = q0 + ((size_t)b * KD + c) * NP;

    for (int i = t; i < 5832; i += 256) pv[i] = 0.f;
    __syncthreads();
    for (int i = t; i < N3; i += 256) {
        int xx = i / R2; int rem = i - xx * R2; int yy = rem / R_; int zz = rem - yy * R_;
        pv[(xx + 2) * 324 + (yy + 2) * 18 + (zz + 2)] = qc[i];
    }
    __syncthreads();

    const float* w = Wdw + (head * KD + c) * 125;   // uniform -> s_loads
    float scl = dsc[head * KD + c], bia = dbi[head * KD + c];

    if (t < R2) {
        int x = t / R_, y = t - (t / R_) * R_;
        float acc[14];
#pragma unroll
        for (int z = 0; z < 14; z++) acc[z] = 0.f;
#pragma unroll
        for (int a = 0; a < 5; a++) {
#pragma unroll
            for (int bb = 0; bb < 5; bb++) {
                const float* base = &pv[(x + a) * 324 + (y + bb) * 18];
                float col[18];
#pragma unroll
                for (int j = 0; j < 18; j++) col[j] = base[j];
#pragma unroll
                for (int cc = 0; cc < 5; cc++) {
                    float wv = w[a * 25 + bb * 5 + cc];
#pragma unroll
                    for (int z = 0; z < 14; z++) acc[z] += wv * col[z + cc];
                }
            }
        }
        float* qo = qc + x * R2 + y * R_;
#pragma unroll
        for (int z = 0; z < 14; z++) qo[z] = acc[z] * scl + bia;
    }
}

// ---------------------------------------------------------------------------
// Attention partial v5: bf16 MFMA (16x16x32). 64 q-rows/block, 4 waves, each
// wave owns 16 n's. QK^T: D=S^T tiles via A=K^T (zero-padded K=32), B=Q.
// Softmax fp32 (plain exp, no max). P->bf16 via per-wave p_lds. PV: A=P, B=V.
// grid (43, B, SPLIT), block 256. Unnormalized (acc, l) partials.
// ---------------------------------------------------------------------------
__global__ __launch_bounds__(256, 3)
void attn_partial(const float* __restrict__ q0, const float* __restrict__ kb,
                  const float* __restrict__ vb, float* __restrict__ pacc,
                  float* __restrict__ pl, const float* __restrict__ abias, int head)
{
    __shared__ short ktT[64][40];      // [m][d], d 0..15 real, 16..31 zeros, pad->40
    __shared__ short vtT[64][72];      // [c][m], pad 72
    __shared__ short plds[4][16][72];  // per-wave P [n][m]
    __shared__ int   mxa[64];          // packed (mx<<8)|my per m
    __shared__ float ab[196];

    const int b = blockIdx.y, z = blockIdx.z;
    const int qbase = blockIdx.x * 64;
    const int t = threadIdx.x;
    const int w = t >> 6;        // wave id
    const int l = t & 63;        // lane
    const int g = l >> 4;        // k-group (0..3)
    const int ln = l & 15;       // fragment M/N index

    if (t < 196) ab[t] = abias[head * R2 + t];

    const float* qq = q0 + (size_t)b * KD * NP;
    const float* kg = kb + (size_t)b * KD * NP;
    const float* vg = vb + (size_t)b * DV * NP;

    // zero-fill ktT d=16..31 (once; in-loop staging only writes d<16)
    {
        int mm = t & 63, dg = t >> 6;
        short4v zz = {0, 0, 0, 0};
        *(short4v*)&ktT[mm][16 + dg * 4] = zz;
    }

    // Q B-frag preload: B[k=d][n], lane: n = ln, k = g*8+j (zero for d>=16)
    const int n_my = qbase + w * 16 + ln;    // < NP always
    short8v qf;
#pragma unroll
    for (int j = 0; j < 8; j++) {
        int d = g * 8 + j;
        qf[j] = (d < KD) ? f2bf(qq[(size_t)d * NP + n_my]) : (short)0;
    }
    const int nmc = n_my < N3 ? n_my : 0;
    const int nx = nmc / R2, ny = (nmc - nx * R2) / R_;

    float4v acc[4];
#pragma unroll
    for (int cs = 0; cs < 4; cs++) acc[cs] = (float4v){0.f, 0.f, 0.f, 0.f};
    float lsum = 0.f;

    const int tEnd = min(z * TPC + TPC, NTILE);
    for (int t0 = z * TPC; t0 < tEnd; t0++) {
        const int m0 = t0 * MT;
        __syncthreads();                         // prev tile consumed
        {   // stage K^T: thread (mm = t&63, dg = t>>6) -> ktT[mm][dg*4..+3]
            int mm = t & 63, dg = t >> 6;
            short4v kv;
#pragma unroll
            for (int i2 = 0; i2 < 4; i2++)
                kv[i2] = f2bf(kg[(size_t)(dg * 4 + i2) * NP + m0 + mm]);
            *(short4v*)&ktT[mm][dg * 4] = kv;
        }
        {   // stage V: thread (c = t>>2, mq = t&3) -> vtT[c][mq*16..+15]
            int c = t >> 2, mq = t & 3;
            const float* vs = vg + (size_t)c * NP + m0 + mq * 16;
            float4 f0 = ((const float4*)vs)[0];
            float4 f1 = ((const float4*)vs)[1];
            float4 f2 = ((const float4*)vs)[2];
            float4 f3 = ((const float4*)vs)[3];
            short8v s0 = { f2bf(f0.x), f2bf(f0.y), f2bf(f0.z), f2bf(f0.w),
                           f2bf(f1.x), f2bf(f1.y), f2bf(f1.z), f2bf(f1.w) };
            short8v s1 = { f2bf(f2.x), f2bf(f2.y), f2bf(f2.z), f2bf(f2.w),
                           f2bf(f3.x), f2bf(f3.y), f2bf(f3.z), f2bf(f3.w) };
            *(short8v*)&vtT[c][mq * 16]     = s0;
            *(short8v*)&vtT[c][mq * 16 + 8] = s1;
        }
        if (t < 64) {
            int m = m0 + t; int mc = m < N3 ? m : 0;
            int mx = mc / R2; int rem = mc - mx * R2; int my = rem / R_;
            mxa[t] = (mx << 8) | my;
        }
        __syncthreads();                         // tile staged

        const int mvalid = N3 - m0;              // >= 56

        // ---- QK^T + softmax, one 16m x 16n subtile at a time ----
#pragma unroll
        for (int ms = 0; ms < 4; ms++) {
            short8v af = *(const short8v*)&ktT[ms * 16 + ln][g * 8];
            float4v zf = {0.f, 0.f, 0.f, 0.f};
            float4v s = __builtin_amdgcn_mfma_f32_16x16x32_bf16(af, qf, zf, 0, 0, 0);
            // lane holds S^T[m = ms*16 + g*4 + r][n = ln]
            int4 pk4 = *(const int4*)&mxa[ms * 16 + g * 4];
            int pka[4] = {pk4.x, pk4.y, pk4.z, pk4.w};
            float p[4];
#pragma unroll
            for (int r = 0; r < 4; r++) {
                int mx = pka[r] >> 8, my = pka[r] & 255;
                float lg = 0.25f * s[r] + ab[iabs(nx - mx) * R_ + iabs(ny - my)];
                int mloc = ms * 16 + g * 4 + r;
                float pe = __expf(lg);
                p[r] = (mloc < mvalid) ? pe : 0.f;
                lsum += p[r];
            }
            short4v pw = { f2bf(p[0]), f2bf(p[1]), f2bf(p[2]), f2bf(p[3]) };
            *(short4v*)&plds[w][ln][ms * 16 + g * 4] = pw;
        }

        // ---- PV: out[n][c] += P[n][m] V[m][c], K=32 chunks ----
#pragma unroll
        for (int ck = 0; ck < 2; ck++) {
            short8v pa = *(const short8v*)&plds[w][ln][ck * 32 + g * 8];
#pragma unroll
            for (int cs = 0; cs < 4; cs++) {
                short8v vf = *(const short8v*)&vtT[cs * 16 + ln][ck * 32 + g * 8];
                acc[cs] = __builtin_amdgcn_mfma_f32_16x16x32_bf16(pa, vf, acc[cs], 0, 0, 0);
            }
        }
    }

    // ---- epilogue ----
    lsum += __shfl_xor(lsum, 16);
    lsum += __shfl_xor(lsum, 32);   // all 4 g-lanes of same ln now hold l[n=ln]

    float* pbase = pacc + (size_t)(b * SPLIT + z) * DV * NP;
    if (l < 16) {
        int n_l = qbase + w * 16 + l;
        if (n_l < N3) pl[(size_t)(b * SPLIT + z) * NP + n_l] = lsum;
    }
    // acc[cs]: lane holds out[n = qbase + w*16 + g*4 + r][c = cs*16 + ln]
    const int n0w = qbase + w * 16 + g * 4;
    if (n0w < N3) {   // N3 % 4 == 0, so whole float4 valid
#pragma unroll
        for (int cs = 0; cs < 4; cs++) {
            int c = cs * 16 + ln;
            *(float4v*)&pbase[(size_t)c * NP + n0w] = acc[cs];
        }
    }
}

// ---------------------------------------------------------------------------
// Combine SPLIT partials: h = (sum_z acc_z) / (sum_z l_z)
// grid (11, B), block 256
// ---------------------------------------------------------------------------
__global__ __launch_bounds__(256)
void attn_combine(const float* __restrict__ pacc, const float* __restrict__ pl,
                  float* __restrict__ h, int head)
{
    int b = blockIdx.y;
    int r = blockIdx.x * 256 + threadIdx.x;
    if (r >= N3) return;
    float l = 0.f;
#pragma unroll
    for (int z = 0; z < SPLIT; z++) l += pl[(size_t)(b * SPLIT + z) * NP + r];
    float inv = 1.f / l;
    float* hb = h + ((size_t)b * C_ + head * DV) * N3 + r;
    const float* pb = pacc + (size_t)b * SPLIT * DV * NP + r;
#pragma unroll
    for (int ch = 0; ch < DV; ch++) {
        float a = 0.f;
#pragma unroll
        for (int z = 0; z < SPLIT; z++) a += pb[(size_t)(z * DV + ch) * NP];
        hb[(size_t)ch * N3] = a * inv;
    }
}

// ---------------------------------------------------------------------------
// Projection: out[o,n] = psc[o]*sum_c Wp[o,c]*relu(h[c,n]) + pbi[o]
// grid (98, B), block 128
// ---------------------------------------------------------------------------
__global__ __launch_bounds__(128)
void proj_kernel(const float* __restrict__ h, const float* __restrict__ Wp,
                 const float* __restrict__ psc, const float* __restrict__ pbi,
                 float* __restrict__ out)
{
    __shared__ float ht[256][28];
    int b = blockIdx.y; int n0 = blockIdx.x * 28; int t = threadIdx.x;

    const float* hb = h + (size_t)b * C_ * N3 + n0;
    for (int i = t; i < 256 * 28; i += 128) {
        int c = i / 28; int j = i - c * 28;
        float v = hb[(size_t)c * N3 + j];
        ht[c][j] = v > 0.f ? v : 0.f;
    }
    __syncthreads();

    int o0 = t, o1 = t + 128;
    float4 a0[7], a1[7];
#pragma unroll
    for (int jb = 0; jb < 7; jb++) { a0[jb] = make_float4(0,0,0,0); a1[jb] = make_float4(0,0,0,0); }

    const float4* w04 = (const float4*)(Wp + (size_t)o0 * 256);
    const float4* w14 = (const float4*)(Wp + (size_t)o1 * 256);
    for (int c4 = 0; c4 < 64; c4++) {
        float4 wa = w04[c4], wb = w14[c4];
        int cb = c4 * 4;
#pragma unroll
        for (int u = 0; u < 4; u++) {
            float W0 = (u == 0) ? wa.x : (u == 1) ? wa.y : (u == 2) ? wa.z : wa.w;
            float W1 = (u == 0) ? wb.x : (u == 1) ? wb.y : (u == 2) ? wb.z : wb.w;
#pragma unroll
            for (int jb = 0; jb < 7; jb++) {
                float4 hv = *(const float4*)&ht[cb + u][4 * jb];
                a0[jb].x += W0 * hv.x; a0[jb].y += W0 * hv.y;
                a0[jb].z += W0 * hv.z; a0[jb].w += W0 * hv.w;
                a1[jb].x += W1 * hv.x; a1[jb].y += W1 * hv.y;
                a1[jb].z += W1 * hv.z; a1[jb].w += W1 * hv.w;
            }
        }
    }

    float s0 = psc[o0], b0 = pbi[o0], s1 = psc[o1], b1 = pbi[o1];
    float* ob0 = out + ((size_t)b * C_ + o0) * N3 + n0;
    float* ob1 = out + ((size_t)b * C_ + o1) * N3 + n0;
#pragma unroll
    for (int jb = 0; jb < 7; jb++) {
        float4 r0 = make_float4(a0[jb].x * s0 + b0, a0[jb].y * s0 + b0,
                                a0[jb].z * s0 + b0, a0[jb].w * s0 + b0);
        float4 r1 = make_float4(a1[jb].x * s1 + b1, a1[jb].y * s1 + b1,
                                a1[jb].z * s1 + b1, a1[jb].w * s1 + b1);
        *(float4*)&ob0[4 * jb] = r0;
        *(float4*)&ob1[4 * jb] = r1;
    }
}

// ---------------------------------------------------------------------------
extern "C" void kernel_launch(void* const* d_in, const int* in_sizes, int n_in,
                              void* d_out, int out_size, void* d_ws, size_t ws_size,
                              hipStream_t stream)
{
    const float* x    = (const float*)d_in[0];
    const float* Wqkv = (const float*)d_in[1];
    const float* qsc  = (const float*)d_in[2];
    const float* qbi  = (const float*)d_in[3];
    const float* Wdw  = (const float*)d_in[4];
    const float* dsc  = (const float*)d_in[5];
    const float* dbi  = (const float*)d_in[6];
    const float* Wp   = (const float*)d_in[7];
    const float* psc  = (const float*)d_in[8];
    const float* pbi  = (const float*)d_in[9];
    const float* ab   = (const float*)d_in[10];
    // d_in[11] = bias_idx: unused (computed analytically)

    float* out = (float*)d_out;
    float* ws  = (float*)d_ws;
    float* q0   = ws;                                     // B*KD*NP
    float* kb   = q0 + (size_t)B_ * KD * NP;              // B*KD*NP
    float* vb   = kb + (size_t)B_ * KD * NP;              // B*DV*NP
    float* h    = vb + (size_t)B_ * DV * NP;              // B*C_*N3
    float* pacc = h  + (size_t)B_ * C_ * N3;              // B*SPLIT*DV*NP
    float* pl   = pacc + (size_t)B_ * SPLIT * DV * NP;    // B*SPLIT*NP

    for (int head = 0; head < NH; head++) {
        qkv_kernel<<<dim3(11, B_, 4), 256, 0, stream>>>(x, h, Wqkv, qsc, qbi, q0, kb, vb, head);
        dwconv_kernel<<<dim3(KD, B_), 256, 0, stream>>>(q0, Wdw, dsc, dbi, head);
        attn_partial<<<dim3(43, B_, SPLIT), 256, 0, stream>>>(q0, kb, vb, pacc, pl, ab, head);
        attn_combine<<<dim3(11, B_), 256, 0, stream>>>(pacc, pl, h, head);
    }
    proj_kernel<<<dim3(98, B_), 128, 0, stream>>>(h, Wp, psc, pbi, out);
}

// Round 7
// 460.013 us; speedup vs baseline: 25.9886x; 1.0891x over previous
//
#include <hip/hip_runtime.h>

#define B_    8
#define C_    256
#define R_    14
#define R2    196
#define N3    2744     // 14^3
#define NP    2752     // padded (43*64): guard-free tile staging
#define NH    4
#define KD    16
#define DV    64
#define QKVO  96       // 2*KD + DV
#define MT    64       // m-tile in attention
#define NTILE 43
#define SPLIT 4
#define TPC   11       // tiles per m-chunk

typedef __attribute__((ext_vector_type(8))) short short8v;
typedef __attribute__((ext_vector_type(4))) short short4v;
typedef __attribute__((ext_vector_type(4))) float float4v;

__device__ __forceinline__ int iabs(int v){ return v < 0 ? -v : v; }

// fp32 -> bf16 round-to-nearest-even (finite inputs)
__device__ __forceinline__ short f2bf(float f){
    union { float f; unsigned int u; } c; c.f = f;
    return (short)((c.u + 0x7FFFu + ((c.u >> 16) & 1u)) >> 16);
}
__device__ __forceinline__ float bf2f(short s){
    union { unsigned int u; float f; } c; c.u = ((unsigned int)(unsigned short)s) << 16;
    return c.f;
}

// ---------------------------------------------------------------------------
// Wp -> bf16 hi/lo split (once). grid 256, block 256.
// ---------------------------------------------------------------------------
__global__ __launch_bounds__(256)
void wprep_kernel(const float* __restrict__ Wp, short* __restrict__ whi,
                  short* __restrict__ wlo)
{
    int i = blockIdx.x * 256 + threadIdx.x;   // 65536 total
    float w = Wp[i];
    short hi = f2bf(w);
    short lo = f2bf(w - bf2f(hi));
    whi[i] = hi; wlo[i] = lo;
}

// ---------------------------------------------------------------------------
// QKV: og 0: q(o 0..15)->fp32 q0; og 1: k(o 16..31)->bf16 kbf[n][16];
//      og 2/3: v(o 32..63 / 64..95)->bf16 vbf[c][NP]
// grid (11, B, 4), block 256
// ---------------------------------------------------------------------------
__global__ __launch_bounds__(256)
void qkv_kernel(const float* __restrict__ x, const float* __restrict__ h,
                const float* __restrict__ W, const float* __restrict__ sc,
                const float* __restrict__ bi,
                float* __restrict__ q0, short* __restrict__ kbf, short* __restrict__ vbf,
                int head)
{
    int b = blockIdx.y;
    int og = blockIdx.z;
    int n = blockIdx.x * 256 + threadIdx.x;
    if (n >= N3) return;

    float f[64];
    const float* xb = x + ((size_t)b * C_ + head * DV) * N3 + n;
    if (head == 0) {
#pragma unroll
        for (int c = 0; c < 64; c++) f[c] = xb[(size_t)c * N3];
    } else {
        const float* hb = h + ((size_t)b * C_ + (head - 1) * DV) * N3 + n;
#pragma unroll
        for (int c = 0; c < 64; c++) f[c] = xb[(size_t)c * N3] + hb[(size_t)c * N3];
    }

    const float* Wh  = W  + head * QKVO * 64;   // uniform -> s_loads
    const float* sch = sc + head * QKVO;
    const float* bih = bi + head * QKVO;

    if (og == 0) {                 // q -> fp32
        float* qo = q0 + (size_t)b * KD * NP + n;
        for (int d = 0; d < 16; d++) {
            int o = d;
            float acc = 0.f;
#pragma unroll
            for (int c = 0; c < 64; c++) acc += Wh[o * 64 + c] * f[c];
            qo[(size_t)d * NP] = acc * sch[o] + bih[o];
        }
    } else if (og == 1) {          // k -> bf16, n-major [n][16]
        short kr[16];
        for (int d = 0; d < 16; d++) {
            int o = 16 + d;
            float acc = 0.f;
#pragma unroll
            for (int c = 0; c < 64; c++) acc += Wh[o * 64 + c] * f[c];
            kr[d] = f2bf(acc * sch[o] + bih[o]);
        }
        short* ko = kbf + (size_t)b * NP * 16 + (size_t)n * 16;
        short8v s0, s1;
#pragma unroll
        for (int i2 = 0; i2 < 8; i2++) { s0[i2] = kr[i2]; s1[i2] = kr[8 + i2]; }
        *(short8v*)ko = s0;
        *(short8v*)(ko + 8) = s1;
    } else {                       // v -> bf16 [c][NP]
        int cb = (og - 2) * 32;
        short* vo = vbf + (size_t)b * DV * NP + n;
        for (int cc = 0; cc < 32; cc++) {
            int o = 32 + cb + cc;
            float acc = 0.f;
#pragma unroll
            for (int c = 0; c < 64; c++) acc += Wh[o * 64 + c] * f[c];
            vo[(size_t)(cb + cc) * NP] = f2bf(acc * sch[o] + bih[o]);
        }
    }
}

// ---------------------------------------------------------------------------
// Depthwise 5x5x5 SAME conv: zero-padded 18^3 LDS volume, branchless.
// grid (KD, B), block 256
// ---------------------------------------------------------------------------
__global__ __launch_bounds__(256)
void dwconv_kernel(float* __restrict__ q0, const float* __restrict__ Wdw,
                   const float* __restrict__ dsc, const float* __restrict__ dbi,
                   int head)
{
    __shared__ float pv[18 * 18 * 18];
    int b = blockIdx.y, c = blockIdx.x;
    int t = threadIdx.x;
    float* qc = q0 + ((size_t)b * KD + c) * NP;

    for (int i = t; i < 5832; i += 256) pv[i] = 0.f;
    __syncthreads();
    for (int i = t; i < N3; i += 256) {
        int xx = i / R2; int rem = i - xx * R2; int yy = rem / R_; int zz = rem - yy * R_;
        pv[(xx + 2) * 324 + (yy + 2) * 18 + (zz + 2)] = qc[i];
    }
    __syncthreads();

    const float* w = Wdw + (head * KD + c) * 125;
    float scl = dsc[head * KD + c], bia = dbi[head * KD + c];

    if (t < R2) {
        int x = t / R_, y = t - (t / R_) * R_;
        float acc[14];
#pragma unroll
        for (int z = 0; z < 14; z++) acc[z] = 0.f;
#pragma unroll
        for (int a = 0; a < 5; a++) {
#pragma unroll
            for (int bb = 0; bb < 5; bb++) {
                const float* base = &pv[(x + a) * 324 + (y + bb) * 18];
                float col[18];
#pragma unroll
                for (int j = 0; j < 18; j++) col[j] = base[j];
#pragma unroll
                for (int cc = 0; cc < 5; cc++) {
                    float wv = w[a * 25 + bb * 5 + cc];
#pragma unroll
                    for (int z = 0; z < 14; z++) acc[z] += wv * col[z + cc];
                }
            }
        }
        float* qo = qc + x * R2 + y * R_;
#pragma unroll
        for (int z = 0; z < 14; z++) qo[z] = acc[z] * scl + bia;
    }
}

// ---------------------------------------------------------------------------
// Attention partial: bf16 MFMA, K/V pre-quantized bf16 -> staging is pure copy.
// grid (43, B, SPLIT), block 256.
// ---------------------------------------------------------------------------
__global__ __launch_bounds__(256, 3)
void attn_partial(const float* __restrict__ q0, const short* __restrict__ kbf,
                  const short* __restrict__ vbf, float* __restrict__ pacc,
                  float* __restrict__ pl, const float* __restrict__ abias, int head)
{
    __shared__ short ktT[64][40];      // [m][d], d 0..15 real, 16..31 zeros, pad->40
    __shared__ short vtT[64][72];      // [c][m], pad 72
    __shared__ short plds[4][16][72];  // per-wave P [n][m]
    __shared__ int   mxa[64];
    __shared__ float ab[196];

    const int b = blockIdx.y, z = blockIdx.z;
    const int qbase = blockIdx.x * 64;
    const int t = threadIdx.x;
    const int w = t >> 6;
    const int l = t & 63;
    const int g = l >> 4;
    const int ln = l & 15;

    if (t < 196) ab[t] = abias[head * R2 + t];

    const float* qq  = q0  + (size_t)b * KD * NP;
    const short* kbs = kbf + (size_t)b * NP * 16;
    const short* vbs = vbf + (size_t)b * DV * NP;

    // zero-fill ktT d=16..31 (in-loop staging only writes d<16)
    {
        int mm = t & 63, dg = t >> 6;
        short4v zz = {0, 0, 0, 0};
        *(short4v*)&ktT[mm][16 + dg * 4] = zz;
    }

    const int n_my = qbase + w * 16 + ln;
    short8v qf;
#pragma unroll
    for (int j = 0; j < 8; j++) {
        int d = g * 8 + j;
        qf[j] = (d < KD) ? f2bf(qq[(size_t)d * NP + n_my]) : (short)0;
    }
    const int nmc = n_my < N3 ? n_my : 0;
    const int nx = nmc / R2, ny = (nmc - nx * R2) / R_;

    float4v acc[4];
#pragma unroll
    for (int cs = 0; cs < 4; cs++) acc[cs] = (float4v){0.f, 0.f, 0.f, 0.f};
    float lsum = 0.f;

    const int tEnd = min(z * TPC + TPC, NTILE);
    for (int t0 = z * TPC; t0 < tEnd; t0++) {
        const int m0 = t0 * MT;
        __syncthreads();
        {   // stage K: thread (mm=t>>2, kq=t&3): b64 copy
            int mm = t >> 2, kq = t & 3;
            short4v kv = *(const short4v*)(kbs + (size_t)(m0 + mm) * 16 + kq * 4);
            *(short4v*)&ktT[mm][kq * 4] = kv;
        }
        {   // stage V: thread (c=t>>2, mq=t&3): 32B copy
            int c = t >> 2, mq = t & 3;
            const short* vs = vbs + (size_t)c * NP + m0 + mq * 16;
            short8v s0 = ((const short8v*)vs)[0];
            short8v s1 = ((const short8v*)vs)[1];
            *(short8v*)&vtT[c][mq * 16]     = s0;
            *(short8v*)&vtT[c][mq * 16 + 8] = s1;
        }
        if (t < 64) {
            int m = m0 + t; int mc = m < N3 ? m : 0;
            int mx = mc / R2; int rem = mc - mx * R2; int my = rem / R_;
            mxa[t] = (mx << 8) | my;
        }
        __syncthreads();

        const int mvalid = N3 - m0;

        // ---- QK^T + softmax ----
#pragma unroll
        for (int ms = 0; ms < 4; ms++) {
            short8v af = *(const short8v*)&ktT[ms * 16 + ln][g * 8];
            float4v zf = {0.f, 0.f, 0.f, 0.f};
            float4v s = __builtin_amdgcn_mfma_f32_16x16x32_bf16(af, qf, zf, 0, 0, 0);
            int4 pk4 = *(const int4*)&mxa[ms * 16 + g * 4];
            int pka[4] = {pk4.x, pk4.y, pk4.z, pk4.w};
            float p[4];
#pragma unroll
            for (int r = 0; r < 4; r++) {
                int mx = pka[r] >> 8, my = pka[r] & 255;
                float lg = 0.25f * s[r] + ab[iabs(nx - mx) * R_ + iabs(ny - my)];
                int mloc = ms * 16 + g * 4 + r;
                float pe = __expf(lg);
                p[r] = (mloc < mvalid) ? pe : 0.f;
                lsum += p[r];
            }
            short4v pw = { f2bf(p[0]), f2bf(p[1]), f2bf(p[2]), f2bf(p[3]) };
            *(short4v*)&plds[w][ln][ms * 16 + g * 4] = pw;
        }

        // ---- PV ----
#pragma unroll
        for (int ck = 0; ck < 2; ck++) {
            short8v pa = *(const short8v*)&plds[w][ln][ck * 32 + g * 8];
#pragma unroll
            for (int cs = 0; cs < 4; cs++) {
                short8v vf = *(const short8v*)&vtT[cs * 16 + ln][ck * 32 + g * 8];
                acc[cs] = __builtin_amdgcn_mfma_f32_16x16x32_bf16(pa, vf, acc[cs], 0, 0, 0);
            }
        }
    }

    // ---- epilogue ----
    lsum += __shfl_xor(lsum, 16);
    lsum += __shfl_xor(lsum, 32);

    float* pbase = pacc + (size_t)(b * SPLIT + z) * DV * NP;
    if (l < 16) {
        int n_l = qbase + w * 16 + l;
        if (n_l < N3) pl[(size_t)(b * SPLIT + z) * NP + n_l] = lsum;
    }
    const int n0w = qbase + w * 16 + g * 4;
    if (n0w < N3) {
#pragma unroll
        for (int cs = 0; cs < 4; cs++) {
            int c = cs * 16 + ln;
            *(float4v*)&pbase[(size_t)c * NP + n0w] = acc[cs];
        }
    }
}

// ---------------------------------------------------------------------------
// Combine SPLIT partials: h = (sum_z acc_z) / (sum_z l_z)
// grid (11, B, 4 ch-groups), block 256
// ---------------------------------------------------------------------------
__global__ __launch_bounds__(256)
void attn_combine(const float* __restrict__ pacc, const float* __restrict__ pl,
                  float* __restrict__ h, int head)
{
    int b = blockIdx.y;
    int ch0 = blockIdx.z * 16;
    int r = blockIdx.x * 256 + threadIdx.x;
    if (r >= N3) return;
    float l = 0.f;
#pragma unroll
    for (int z = 0; z < SPLIT; z++) l += pl[(size_t)(b * SPLIT + z) * NP + r];
    float inv = 1.f / l;
    float* hb = h + ((size_t)b * C_ + head * DV) * N3 + r;
    const float* pb = pacc + (size_t)b * SPLIT * DV * NP + r;
#pragma unroll
    for (int cc = 0; cc < 16; cc++) {
        int ch = ch0 + cc;
        float a = 0.f;
#pragma unroll
        for (int z = 0; z < SPLIT; z++) a += pb[(size_t)(z * DV + ch) * NP];
        hb[(size_t)ch * N3] = a * inv;
    }
}

// ---------------------------------------------------------------------------
// Projection v7: split-bf16 MFMA. out = psc*(Wp @ relu(h)) + pbi
// Whi@hhi + Whi@hlo + Wlo@hhi (exact to ~2^-18).
// grid (43 n-tiles, B), block 256 (4 waves; wave w -> o range 64w..64w+63)
// ---------------------------------------------------------------------------
__global__ __launch_bounds__(256, 2)
void proj_kernel(const float* __restrict__ h, const short* __restrict__ whi,
                 const short* __restrict__ wlo, const float* __restrict__ psc,
                 const float* __restrict__ pbi, float* __restrict__ out)
{
    __shared__ short hhi[64][40];   // [n][c-chunk 32], stride 40: conflict-free b128
    __shared__ short hlo[64][40];

    const int b = blockIdx.y;
    const int n0 = blockIdx.x * 64;
    const int t = threadIdx.x;
    const int w = t >> 6, l = t & 63, g = l >> 4, ln = l & 15;

    float4v acc[4][4];   // [os][ns]
#pragma unroll
    for (int os = 0; os < 4; os++)
#pragma unroll
        for (int ns = 0; ns < 4; ns++) acc[os][ns] = (float4v){0.f, 0.f, 0.f, 0.f};

    const float* hb = h + (size_t)b * C_ * N3;
    const int sc = t >> 3;            // staging c (0..31)
    const int sn = (t & 7) * 8;       // staging n base

    for (int c0 = 0; c0 < 256; c0 += 32) {
        __syncthreads();   // prev chunk consumed
        {   // stage relu(h) chunk transposed, hi/lo split
            const float* hsrc = hb + (size_t)(c0 + sc) * N3 + n0 + sn;
            float4 f0 = ((const float4*)hsrc)[0];
            float4 f1 = ((const float4*)hsrc)[1];
            float va[8] = { f0.x, f0.y, f0.z, f0.w, f1.x, f1.y, f1.z, f1.w };
#pragma unroll
            for (int u = 0; u < 8; u++) {
                float v = va[u] > 0.f ? va[u] : 0.f;
                short hi = f2bf(v);
                short lo = f2bf(v - bf2f(hi));
                hhi[sn + u][sc] = hi;
                hlo[sn + u][sc] = lo;
            }
        }
        __syncthreads();

        // W frags (direct from L2), rows o = 64w + os*16 + ln
        short8v wh[4], wl[4];
#pragma unroll
        for (int os = 0; os < 4; os++) {
            size_t off = (size_t)(64 * w + os * 16 + ln) * 256 + c0 + g * 8;
            wh[os] = *(const short8v*)(whi + off);
            wl[os] = *(const short8v*)(wlo + off);
        }
#pragma unroll
        for (int ns = 0; ns < 4; ns++) {
            short8v bh = *(const short8v*)&hhi[ns * 16 + ln][g * 8];
            short8v bl = *(const short8v*)&hlo[ns * 16 + ln][g * 8];
#pragma unroll
            for (int os = 0; os < 4; os++) {
                acc[os][ns] = __builtin_amdgcn_mfma_f32_16x16x32_bf16(wh[os], bh, acc[os][ns], 0, 0, 0);
                acc[os][ns] = __builtin_amdgcn_mfma_f32_16x16x32_bf16(wh[os], bl, acc[os][ns], 0, 0, 0);
                acc[os][ns] = __builtin_amdgcn_mfma_f32_16x16x32_bf16(wl[os], bh, acc[os][ns], 0, 0, 0);
            }
        }
    }

    // epilogue: D[o = 64w+os*16+g*4+r][n = n0+ns*16+ln]
    float* ob = out + (size_t)b * C_ * N3;
#pragma unroll
    for (int os = 0; os < 4; os++) {
#pragma unroll
        for (int r = 0; r < 4; r++) {
            int o = 64 * w + os * 16 + g * 4 + r;
            float s0 = psc[o], b0 = pbi[o];
#pragma unroll
            for (int ns = 0; ns < 4; ns++) {
                int n = n0 + ns * 16 + ln;
                if (n < N3) ob[(size_t)o * N3 + n] = acc[os][ns][r] * s0 + b0;
            }
        }
    }
}

// ---------------------------------------------------------------------------
extern "C" void kernel_launch(void* const* d_in, const int* in_sizes, int n_in,
                              void* d_out, int out_size, void* d_ws, size_t ws_size,
                              hipStream_t stream)
{
    const float* x    = (const float*)d_in[0];
    const float* Wqkv = (const float*)d_in[1];
    const float* qsc  = (const float*)d_in[2];
    const float* qbi  = (const float*)d_in[3];
    const float* Wdw  = (const float*)d_in[4];
    const float* dsc  = (const float*)d_in[5];
    const float* dbi  = (const float*)d_in[6];
    const float* Wp   = (const float*)d_in[7];
    const float* psc  = (const float*)d_in[8];
    const float* pbi  = (const float*)d_in[9];
    const float* ab   = (const float*)d_in[10];
    // d_in[11] = bias_idx: unused (computed analytically)

    float* out = (float*)d_out;
    char*  wsb = (char*)d_ws;
    float* q0   = (float*)wsb;                                  // B*KD*NP f32
    short* kbf  = (short*)(q0 + (size_t)B_ * KD * NP);          // B*NP*16 bf16
    short* vbf  = kbf + (size_t)B_ * NP * 16;                   // B*DV*NP bf16
    float* h    = (float*)(vbf + (size_t)B_ * DV * NP);         // B*C*N3 f32
    float* pacc = h + (size_t)B_ * C_ * N3;                     // B*SPLIT*DV*NP f32
    float* pl   = pacc + (size_t)B_ * SPLIT * DV * NP;          // B*SPLIT*NP f32
    short* whi  = (short*)(pl + (size_t)B_ * SPLIT * NP);       // 256*256 bf16
    short* wlo  = whi + 256 * 256;                              // 256*256 bf16

    wprep_kernel<<<256, 256, 0, stream>>>(Wp, whi, wlo);

    for (int head = 0; head < NH; head++) {
        qkv_kernel<<<dim3(11, B_, 4), 256, 0, stream>>>(x, h, Wqkv, qsc, qbi, q0, kbf, vbf, head);
        dwconv_kernel<<<dim3(KD, B_), 256, 0, stream>>>(q0, Wdw, dsc, dbi, head);
        attn_partial<<<dim3(43, B_, SPLIT), 256, 0, stream>>>(q0, kbf, vbf, pacc, pl, ab, head);
        attn_combine<<<dim3(11, B_, 4), 256, 0, stream>>>(pacc, pl, h, head);
    }
    proj_kernel<<<dim3(43, B_), 256, 0, stream>>>(h, whi, wlo, psc, pbi, out);
}

// Round 8
// 446.220 us; speedup vs baseline: 26.7919x; 1.0309x over previous
//
#include <hip/hip_runtime.h>

#define B_    8
#define C_    256
#define R_    14
#define R2    196
#define N3    2744     // 14^3
#define NP    2752     // padded (43*64): guard-free tile staging
#define NH    4
#define KD    16
#define DV    64
#define QKVO  96       // 2*KD + DV
#define MT    64       // m-tile in attention
#define NTILE 43
#define SPLIT 4
#define TPC   11       // tiles per m-chunk

#define SC2   0.36067376f   // 0.25 * log2(e)
#define LOG2E 1.44269504f

typedef __attribute__((ext_vector_type(8))) short short8v;
typedef __attribute__((ext_vector_type(4))) short short4v;
typedef __attribute__((ext_vector_type(4))) float float4v;

__device__ __forceinline__ int iabs(int v){ return v < 0 ? -v : v; }

// fp32 -> bf16 round-to-nearest-even (finite inputs)
__device__ __forceinline__ short f2bf(float f){
    union { float f; unsigned int u; } c; c.f = f;
    return (short)((c.u + 0x7FFFu + ((c.u >> 16) & 1u)) >> 16);
}
__device__ __forceinline__ float bf2f(short s){
    union { unsigned int u; float f; } c; c.u = ((unsigned int)(unsigned short)s) << 16;
    return c.f;
}

// ---------------------------------------------------------------------------
// Wp -> bf16 hi/lo split (once). grid 256, block 256.
// ---------------------------------------------------------------------------
__global__ __launch_bounds__(256)
void wprep_kernel(const float* __restrict__ Wp, short* __restrict__ whi,
                  short* __restrict__ wlo)
{
    int i = blockIdx.x * 256 + threadIdx.x;   // 65536 total
    float w = Wp[i];
    short hi = f2bf(w);
    short lo = f2bf(w - bf2f(hi));
    whi[i] = hi; wlo[i] = lo;
}

// ---------------------------------------------------------------------------
// QKV: og 0: q(o 0..15)->fp32 q0; og 1: k(o 16..31)->bf16 kbf[n][16];
//      og 2/3: v(o 32..63 / 64..95)->bf16 vbf[c][NP]
// Pad rows n in [N3, NP) are ZEROED (attn relies on this for guard-free tiles).
// grid (11, B, 4), block 256
// ---------------------------------------------------------------------------
__global__ __launch_bounds__(256)
void qkv_kernel(const float* __restrict__ x, const float* __restrict__ h,
                const float* __restrict__ W, const float* __restrict__ sc,
                const float* __restrict__ bi,
                float* __restrict__ q0, short* __restrict__ kbf, short* __restrict__ vbf,
                int head)
{
    int b = blockIdx.y;
    int og = blockIdx.z;
    int n = blockIdx.x * 256 + threadIdx.x;
    if (n >= N3) {
        if (n < NP) {   // zero the pad rows once per call (deterministic)
            if (og == 0) {
                float* qo = q0 + (size_t)b * KD * NP + n;
#pragma unroll
                for (int d = 0; d < KD; d++) qo[(size_t)d * NP] = 0.f;
            } else if (og == 1) {
                short8v z8 = {0,0,0,0,0,0,0,0};
                short* ko = kbf + (size_t)b * NP * 16 + (size_t)n * 16;
                *(short8v*)ko = z8; *(short8v*)(ko + 8) = z8;
            } else {
                int cb = (og - 2) * 32;
                short* vo = vbf + (size_t)b * DV * NP + n;
#pragma unroll
                for (int cc = 0; cc < 32; cc++) vo[(size_t)(cb + cc) * NP] = 0;
            }
        }
        return;
    }

    float f[64];
    const float* xb = x + ((size_t)b * C_ + head * DV) * N3 + n;
    if (head == 0) {
#pragma unroll
        for (int c = 0; c < 64; c++) f[c] = xb[(size_t)c * N3];
    } else {
        const float* hb = h + ((size_t)b * C_ + (head - 1) * DV) * N3 + n;
#pragma unroll
        for (int c = 0; c < 64; c++) f[c] = xb[(size_t)c * N3] + hb[(size_t)c * N3];
    }

    const float* Wh  = W  + head * QKVO * 64;   // uniform -> s_loads
    const float* sch = sc + head * QKVO;
    const float* bih = bi + head * QKVO;

    if (og == 0) {                 // q -> fp32
        float* qo = q0 + (size_t)b * KD * NP + n;
        for (int d = 0; d < 16; d++) {
            int o = d;
            float acc = 0.f;
#pragma unroll
            for (int c = 0; c < 64; c++) acc += Wh[o * 64 + c] * f[c];
            qo[(size_t)d * NP] = acc * sch[o] + bih[o];
        }
    } else if (og == 1) {          // k -> bf16, n-major [n][16]
        short kr[16];
        for (int d = 0; d < 16; d++) {
            int o = 16 + d;
            float acc = 0.f;
#pragma unroll
            for (int c = 0; c < 64; c++) acc += Wh[o * 64 + c] * f[c];
            kr[d] = f2bf(acc * sch[o] + bih[o]);
        }
        short* ko = kbf + (size_t)b * NP * 16 + (size_t)n * 16;
        short8v s0, s1;
#pragma unroll
        for (int i2 = 0; i2 < 8; i2++) { s0[i2] = kr[i2]; s1[i2] = kr[8 + i2]; }
        *(short8v*)ko = s0;
        *(short8v*)(ko + 8) = s1;
    } else {                       // v -> bf16 [c][NP]
        int cb = (og - 2) * 32;
        short* vo = vbf + (size_t)b * DV * NP + n;
        for (int cc = 0; cc < 32; cc++) {
            int o = 32 + cb + cc;
            float acc = 0.f;
#pragma unroll
            for (int c = 0; c < 64; c++) acc += Wh[o * 64 + c] * f[c];
            vo[(size_t)(cb + cc) * NP] = f2bf(acc * sch[o] + bih[o]);
        }
    }
}

// ---------------------------------------------------------------------------
// Depthwise 5x5x5 SAME conv: zero-padded 18^3 LDS volume, branchless.
// grid (KD, B), block 256
// ---------------------------------------------------------------------------
__global__ __launch_bounds__(256)
void dwconv_kernel(float* __restrict__ q0, const float* __restrict__ Wdw,
                   const float* __restrict__ dsc, const float* __restrict__ dbi,
                   int head)
{
    __shared__ float pv[18 * 18 * 18];
    int b = blockIdx.y, c = blockIdx.x;
    int t = threadIdx.x;
    float* qc = q0 + ((size_t)b * KD + c) * NP;

    for (int i = t; i < 5832; i += 256) pv[i] = 0.f;
    __syncthreads();
    for (int i = t; i < N3; i += 256) {
        int xx = i / R2; int rem = i - xx * R2; int yy = rem / R_; int zz = rem - yy * R_;
        pv[(xx + 2) * 324 + (yy + 2) * 18 + (zz + 2)] = qc[i];
    }
    __syncthreads();

    const float* w = Wdw + (head * KD + c) * 125;
    float scl = dsc[head * KD + c], bia = dbi[head * KD + c];

    if (t < R2) {
        int x = t / R_, y = t - (t / R_) * R_;
        float acc[14];
#pragma unroll
        for (int z = 0; z < 14; z++) acc[z] = 0.f;
#pragma unroll
        for (int a = 0; a < 5; a++) {
#pragma unroll
            for (int bb = 0; bb < 5; bb++) {
                const float* base = &pv[(x + a) * 324 + (y + bb) * 18];
                float col[18];
#pragma unroll
                for (int j = 0; j < 18; j++) col[j] = base[j];
#pragma unroll
                for (int cc = 0; cc < 5; cc++) {
                    float wv = w[a * 25 + bb * 5 + cc];
#pragma unroll
                    for (int z = 0; z < 14; z++) acc[z] += wv * col[z + cc];
                }
            }
        }
        float* qo = qc + x * R2 + y * R_;
#pragma unroll
        for (int z = 0; z < 14; z++) qo[z] = acc[z] * scl + bia;
    }
}

// ---------------------------------------------------------------------------
// Attention partial v8: bf16 MFMA + lean softmax:
//   - v_sad_u32 bias indexing (3 ops vs ~7)
//   - exp2-domain bias table (ab2 = ab*log2e), native exp2f
//   - no boundary guards: pad K/V rows zeroed, pad-m sentinel -> idx clamp to
//     ab2[196] = -20000 -> p = 0 exactly
//   - v_cvt_pk_bf16_f32 for P -> bf16
// grid (43, B, SPLIT), block 256.
// ---------------------------------------------------------------------------
__global__ __launch_bounds__(256, 4)
void attn_partial(const float* __restrict__ q0, const short* __restrict__ kbf,
                  const short* __restrict__ vbf, float* __restrict__ pacc,
                  float* __restrict__ pl, const float* __restrict__ abias, int head)
{
    __shared__ short ktT[64][40];      // [m][d], d 0..15 real, 16..31 zeros, pad->40
    __shared__ short vtT[64][72];      // [c][m], pad 72
    __shared__ short plds[4][16][72];  // per-wave P [n][m]
    __shared__ int   mxa[64];
    __shared__ float ab2[200];         // bias * log2e; [196..199] = -20000 sentinel

    const int b = blockIdx.y, z = blockIdx.z;
    const int qbase = blockIdx.x * 64;
    const int t = threadIdx.x;
    const int w = t >> 6;
    const int l = t & 63;
    const int g = l >> 4;
    const int ln = l & 15;

    if (t < 196) ab2[t] = abias[head * R2 + t] * LOG2E;
    else if (t < 200) ab2[t] = -20000.0f;

    const float* qq  = q0  + (size_t)b * KD * NP;
    const short* kbs = kbf + (size_t)b * NP * 16;
    const short* vbs = vbf + (size_t)b * DV * NP;

    // zero-fill ktT d=16..31 (in-loop staging only writes d<16)
    {
        int mm = t & 63, dg = t >> 6;
        short4v zz = {0, 0, 0, 0};
        *(short4v*)&ktT[mm][16 + dg * 4] = zz;
    }

    const int n_my = qbase + w * 16 + ln;
    short8v qf;
#pragma unroll
    for (int j = 0; j < 8; j++) {
        int d = g * 8 + j;
        qf[j] = (d < KD) ? f2bf(qq[(size_t)d * NP + n_my]) : (short)0;
    }
    const int nmc = n_my < N3 ? n_my : 0;
    const int nx = nmc / R2, ny = (nmc - nx * R2) / R_;

    float4v acc[4];
#pragma unroll
    for (int cs = 0; cs < 4; cs++) acc[cs] = (float4v){0.f, 0.f, 0.f, 0.f};
    float lsum = 0.f;

    const int tEnd = min(z * TPC + TPC, NTILE);
    for (int t0 = z * TPC; t0 < tEnd; t0++) {
        const int m0 = t0 * MT;
        __syncthreads();
        {   // stage K: thread (mm=t>>2, kq=t&3): b64 copy (pad rows are zeros)
            int mm = t >> 2, kq = t & 3;
            short4v kv = *(const short4v*)(kbs + (size_t)(m0 + mm) * 16 + kq * 4);
            *(short4v*)&ktT[mm][kq * 4] = kv;
        }
        {   // stage V: thread (c=t>>2, mq=t&3): 32B copy
            int c = t >> 2, mq = t & 3;
            const short* vs = vbs + (size_t)c * NP + m0 + mq * 16;
            short8v s0 = ((const short8v*)vs)[0];
            short8v s1 = ((const short8v*)vs)[1];
            *(short8v*)&vtT[c][mq * 16]     = s0;
            *(short8v*)&vtT[c][mq * 16 + 8] = s1;
        }
        if (t < 64) {
            int m = m0 + t;
            int mx, my;
            if (m < N3) { mx = m / R2; int rem = m - mx * R2; my = rem / R_; }
            else        { mx = 220; my = 220; }   // sentinel -> idx >= 196 -> clamp
            mxa[t] = (mx << 8) | my;
        }
        __syncthreads();

        // ---- QK^T + softmax (guard-free) ----
#pragma unroll
        for (int ms = 0; ms < 4; ms++) {
            short8v af = *(const short8v*)&ktT[ms * 16 + ln][g * 8];
            float4v zf = {0.f, 0.f, 0.f, 0.f};
            float4v s = __builtin_amdgcn_mfma_f32_16x16x32_bf16(af, qf, zf, 0, 0, 0);
            int4 pk4 = *(const int4*)&mxa[ms * 16 + g * 4];
            int pka[4] = {pk4.x, pk4.y, pk4.z, pk4.w};
            float p[4];
#pragma unroll
            for (int r = 0; r < 4; r++) {
                int mx = pka[r] >> 8, my = pka[r] & 255;
                int dx, idx;
                asm("v_sad_u32 %0, %1, %2, 0" : "=v"(dx) : "v"(nx), "v"(mx));
                int t14 = dx * 14;
                asm("v_sad_u32 %0, %1, %2, %3" : "=v"(idx) : "v"(ny), "v"(my), "v"(t14));
                idx = idx < 196 ? idx : 196;
                float lg2 = fmaf(s[r], SC2, ab2[idx]);
                p[r] = exp2f(lg2);
                lsum += p[r];
            }
            unsigned pk01, pk23;
            asm("v_cvt_pk_bf16_f32 %0, %1, %2" : "=v"(pk01) : "v"(p[0]), "v"(p[1]));
            asm("v_cvt_pk_bf16_f32 %0, %1, %2" : "=v"(pk23) : "v"(p[2]), "v"(p[3]));
            uint2 pw = make_uint2(pk01, pk23);
            *(uint2*)&plds[w][ln][ms * 16 + g * 4] = pw;
        }

        // ---- PV ----
#pragma unroll
        for (int ck = 0; ck < 2; ck++) {
            short8v pa = *(const short8v*)&plds[w][ln][ck * 32 + g * 8];
#pragma unroll
            for (int cs = 0; cs < 4; cs++) {
                short8v vf = *(const short8v*)&vtT[cs * 16 + ln][ck * 32 + g * 8];
                acc[cs] = __builtin_amdgcn_mfma_f32_16x16x32_bf16(pa, vf, acc[cs], 0, 0, 0);
            }
        }
    }

    // ---- epilogue ----
    lsum += __shfl_xor(lsum, 16);
    lsum += __shfl_xor(lsum, 32);

    float* pbase = pacc + (size_t)(b * SPLIT + z) * DV * NP;
    if (l < 16) {
        int n_l = qbase + w * 16 + l;
        if (n_l < N3) pl[(size_t)(b * SPLIT + z) * NP + n_l] = lsum;
    }
    const int n0w = qbase + w * 16 + g * 4;
    if (n0w < N3) {
#pragma unroll
        for (int cs = 0; cs < 4; cs++) {
            int c = cs * 16 + ln;
            *(float4v*)&pbase[(size_t)c * NP + n0w] = acc[cs];
        }
    }
}

// ---------------------------------------------------------------------------
// Combine SPLIT partials: h = (sum_z acc_z) / (sum_z l_z)
// grid (11, B, 4 ch-groups), block 256
// ---------------------------------------------------------------------------
__global__ __launch_bounds__(256)
void attn_combine(const float* __restrict__ pacc, const float* __restrict__ pl,
                  float* __restrict__ h, int head)
{
    int b = blockIdx.y;
    int ch0 = blockIdx.z * 16;
    int r = blockIdx.x * 256 + threadIdx.x;
    if (r >= N3) return;
    float l = 0.f;
#pragma unroll
    for (int z = 0; z < SPLIT; z++) l += pl[(size_t)(b * SPLIT + z) * NP + r];
    float inv = 1.f / l;
    float* hb = h + ((size_t)b * C_ + head * DV) * N3 + r;
    const float* pb = pacc + (size_t)b * SPLIT * DV * NP + r;
#pragma unroll
    for (int cc = 0; cc < 16; cc++) {
        int ch = ch0 + cc;
        float a = 0.f;
#pragma unroll
        for (int z = 0; z < SPLIT; z++) a += pb[(size_t)(z * DV + ch) * NP];
        hb[(size_t)ch * N3] = a * inv;
    }
}

// ---------------------------------------------------------------------------
// Projection: split-bf16 MFMA. out = psc*(Wp @ relu(h)) + pbi
// grid (43 n-tiles, B), block 256
// ---------------------------------------------------------------------------
__global__ __launch_bounds__(256, 2)
void proj_kernel(const float* __restrict__ h, const short* __restrict__ whi,
                 const short* __restrict__ wlo, const float* __restrict__ psc,
                 const float* __restrict__ pbi, float* __restrict__ out)
{
    __shared__ short hhi[64][40];
    __shared__ short hlo[64][40];

    const int b = blockIdx.y;
    const int n0 = blockIdx.x * 64;
    const int t = threadIdx.x;
    const int w = t >> 6, l = t & 63, g = l >> 4, ln = l & 15;

    float4v acc[4][4];
#pragma unroll
    for (int os = 0; os < 4; os++)
#pragma unroll
        for (int ns = 0; ns < 4; ns++) acc[os][ns] = (float4v){0.f, 0.f, 0.f, 0.f};

    const float* hb = h + (size_t)b * C_ * N3;
    const int sc = t >> 3;
    const int sn = (t & 7) * 8;

    for (int c0 = 0; c0 < 256; c0 += 32) {
        __syncthreads();
        {
            const float* hsrc = hb + (size_t)(c0 + sc) * N3 + n0 + sn;
            float4 f0 = ((const float4*)hsrc)[0];
            float4 f1 = ((const float4*)hsrc)[1];
            float va[8] = { f0.x, f0.y, f0.z, f0.w, f1.x, f1.y, f1.z, f1.w };
#pragma unroll
            for (int u = 0; u < 8; u++) {
                float v = va[u] > 0.f ? va[u] : 0.f;
                short hi = f2bf(v);
                short lo = f2bf(v - bf2f(hi));
                hhi[sn + u][sc] = hi;
                hlo[sn + u][sc] = lo;
            }
        }
        __syncthreads();

        short8v wh[4], wl[4];
#pragma unroll
        for (int os = 0; os < 4; os++) {
            size_t off = (size_t)(64 * w + os * 16 + ln) * 256 + c0 + g * 8;
            wh[os] = *(const short8v*)(whi + off);
            wl[os] = *(const short8v*)(wlo + off);
        }
#pragma unroll
        for (int ns = 0; ns < 4; ns++) {
            short8v bh = *(const short8v*)&hhi[ns * 16 + ln][g * 8];
            short8v bl = *(const short8v*)&hlo[ns * 16 + ln][g * 8];
#pragma unroll
            for (int os = 0; os < 4; os++) {
                acc[os][ns] = __builtin_amdgcn_mfma_f32_16x16x32_bf16(wh[os], bh, acc[os][ns], 0, 0, 0);
                acc[os][ns] = __builtin_amdgcn_mfma_f32_16x16x32_bf16(wh[os], bl, acc[os][ns], 0, 0, 0);
                acc[os][ns] = __builtin_amdgcn_mfma_f32_16x16x32_bf16(wl[os], bh, acc[os][ns], 0, 0, 0);
            }
        }
    }

    float* ob = out + (size_t)b * C_ * N3;
#pragma unroll
    for (int os = 0; os < 4; os++) {
#pragma unroll
        for (int r = 0; r < 4; r++) {
            int o = 64 * w + os * 16 + g * 4 + r;
            float s0 = psc[o], b0 = pbi[o];
#pragma unroll
            for (int ns = 0; ns < 4; ns++) {
                int n = n0 + ns * 16 + ln;
                if (n < N3) ob[(size_t)o * N3 + n] = acc[os][ns][r] * s0 + b0;
            }
        }
    }
}

// ---------------------------------------------------------------------------
extern "C" void kernel_launch(void* const* d_in, const int* in_sizes, int n_in,
                              void* d_out, int out_size, void* d_ws, size_t ws_size,
                              hipStream_t stream)
{
    const float* x    = (const float*)d_in[0];
    const float* Wqkv = (const float*)d_in[1];
    const float* qsc  = (const float*)d_in[2];
    const float* qbi  = (const float*)d_in[3];
    const float* Wdw  = (const float*)d_in[4];
    const float* dsc  = (const float*)d_in[5];
    const float* dbi  = (const float*)d_in[6];
    const float* Wp   = (const float*)d_in[7];
    const float* psc  = (const float*)d_in[8];
    const float* pbi  = (const float*)d_in[9];
    const float* ab   = (const float*)d_in[10];
    // d_in[11] = bias_idx: unused (computed analytically)

    float* out = (float*)d_out;
    char*  wsb = (char*)d_ws;
    float* q0   = (float*)wsb;                                  // B*KD*NP f32
    short* kbf  = (short*)(q0 + (size_t)B_ * KD * NP);          // B*NP*16 bf16
    short* vbf  = kbf + (size_t)B_ * NP * 16;                   // B*DV*NP bf16
    float* h    = (float*)(vbf + (size_t)B_ * DV * NP);         // B*C*N3 f32
    float* pacc = h + (size_t)B_ * C_ * N3;                     // B*SPLIT*DV*NP f32
    float* pl   = pacc + (size_t)B_ * SPLIT * DV * NP;          // B*SPLIT*NP f32
    short* whi  = (short*)(pl + (size_t)B_ * SPLIT * NP);       // 256*256 bf16
    short* wlo  = whi + 256 * 256;                              // 256*256 bf16

    wprep_kernel<<<256, 256, 0, stream>>>(Wp, whi, wlo);

    for (int head = 0; head < NH; head++) {
        qkv_kernel<<<dim3(11, B_, 4), 256, 0, stream>>>(x, h, Wqkv, qsc, qbi, q0, kbf, vbf, head);
        dwconv_kernel<<<dim3(KD, B_), 256, 0, stream>>>(q0, Wdw, dsc, dbi, head);
        attn_partial<<<dim3(43, B_, SPLIT), 256, 0, stream>>>(q0, kbf, vbf, pacc, pl, ab, head);
        attn_combine<<<dim3(11, B_, 4), 256, 0, stream>>>(pacc, pl, h, head);
    }
    proj_kernel<<<dim3(43, B_), 256, 0, stream>>>(h, whi, wlo, psc, pbi, out);
}